// Round 5
// baseline (12919.820 us; speedup 1.0000x reference)
//
#include <hip/hip_runtime.h>
#include <stdint.h>

typedef unsigned int u32;
typedef unsigned long long u64;

// ---------------------------------------------------------------------------
// Threefry-2x32, 20 rounds — bit-exact replica of JAX's threefry2x32 primitive.
// ---------------------------------------------------------------------------
__host__ __device__ __forceinline__ void tf2x32(u32 k0, u32 k1, u32 x0, u32 x1,
                                                u32& o0, u32& o1) {
  u32 k2 = k0 ^ k1 ^ 0x1BD11BDAu;
  x0 += k0; x1 += k1;
#define TFR(r) { x0 += x1; x1 = (x1 << (r)) | (x1 >> (32 - (r))); x1 ^= x0; }
  TFR(13) TFR(15) TFR(26) TFR(6)   x0 += k1; x1 += k2 + 1u;
  TFR(17) TFR(29) TFR(16) TFR(24)  x0 += k2; x1 += k0 + 2u;
  TFR(13) TFR(15) TFR(26) TFR(6)   x0 += k0; x1 += k1 + 3u;
  TFR(17) TFR(29) TFR(16) TFR(24)  x0 += k1; x1 += k2 + 4u;
  TFR(13) TFR(15) TFR(26) TFR(6)   x0 += k2; x1 += k0 + 5u;
#undef TFR
  o0 = x0; o1 = x1;
}

// stoch_act: p = clip((y+1)*0.5, 0, 1); u from partitionable random bits of
// flat index j: bits = o0 ^ o1 of TF(key, (0, j)). Returns true if out = -1.
__device__ __forceinline__ bool act_neg(float y, u32 k0, u32 k1, u32 j) {
  u32 o0, o1;
  tf2x32(k0, k1, 0u, j, o0, o1);
  u32 bits = o0 ^ o1;
  float u = __uint_as_float(0x3f800000u | (bits >> 9)) - 1.0f;
  float t = (y + 1.0f) * 0.5f;
  float p = fminf(fmaxf(t, 0.0f), 1.0f);
  return !(u < p);
}

// ---------------------------------------------------------------------------
// Weight packing (bit = 1 iff weight < 0). Conv: [C][Cin][3][3] -> [C][9][W].
// ---------------------------------------------------------------------------
__global__ void k_pack_convw(const float* __restrict__ w, u32* __restrict__ pw,
                             int Cout, int Cin) {
  int Wi = Cin >> 5;
  int idx = blockIdx.x * blockDim.x + threadIdx.x;
  int total = Cout * 9 * Wi;
  if (idx >= total) return;
  int wi = idx % Wi;
  int t = (idx / Wi) % 9;
  int co = idx / (Wi * 9);
  int kh = t / 3, kw = t % 3;
  u32 word = 0;
  for (int b = 0; b < 32; ++b) {
    int ci = wi * 32 + b;
    float v = w[((co * Cin + ci) * 3 + kh) * 3 + kw];
    word |= (v < 0.0f ? 1u : 0u) << b;
  }
  pw[idx] = word;
}

// FC weight pack, transposed for coalesced lane=o loads: pwT[k4][o][j].
__global__ void k_pack_fcwT(const float* __restrict__ w, u32* __restrict__ pwT,
                            int O, int K) {
  int KW = K >> 5;
  int idx = blockIdx.x * blockDim.x + threadIdx.x;
  if (idx >= O * KW) return;
  int kw = idx % KW, o = idx / KW;
  u32 word = 0;
  for (int b = 0; b < 32; ++b)
    word |= (w[(size_t)o * K + kw * 32 + b] < 0.0f ? 1u : 0u) << b;
  int k4 = kw >> 2, j = kw & 3;
  pwT[((size_t)k4 * O + o) * 4 + j] = word;
}

// FC weight pack, row-major (fc3).
__global__ void k_pack_fcw(const float* __restrict__ w, u32* __restrict__ pw,
                           int O, int K) {
  int KW = K >> 5;
  int idx = blockIdx.x * blockDim.x + threadIdx.x;
  if (idx >= O * KW) return;
  int kw = idx % KW, o = idx / KW;
  u32 word = 0;
  for (int b = 0; b < 32; ++b)
    word |= (w[o * K + kw * 32 + b] < 0.0f ? 1u : 0u) << b;
  pw[idx] = word;
}

// ---------------------------------------------------------------------------
// conv1: fp32 x [64][3][32][32], binarized w1, +b1, stoch_act key0,
// output channel-packed [64][32][32][4]. One wave per (n,y,x); lane = co.
// ---------------------------------------------------------------------------
__global__ __launch_bounds__(256) void k_conv1(
    const float* __restrict__ x, const float* __restrict__ w1,
    const float* __restrict__ b1, u32 k0, u32 k1, u32* __restrict__ out) {
  int wave = (blockIdx.x * 256 + threadIdx.x) >> 6;
  int lane = threadIdx.x & 63;
  int n = wave >> 10;
  int rem = wave & 1023;
  int y = rem >> 5, xx = rem & 31;

  float xv[27];
#pragma unroll
  for (int ci = 0; ci < 3; ++ci)
#pragma unroll
    for (int dy = -1; dy <= 1; ++dy)
#pragma unroll
      for (int dx = -1; dx <= 1; ++dx) {
        int gy = y + dy, gx = xx + dx;
        float v = 0.0f;
        if ((unsigned)gy < 32u && (unsigned)gx < 32u)
          v = x[((n * 3 + ci) * 32 + gy) * 32 + gx];
        xv[(ci * 3 + (dy + 1)) * 3 + (dx + 1)] = v;
      }

  u64 bm[2];
#pragma unroll
  for (int h = 0; h < 2; ++h) {
    int co = lane + h * 64;
    float acc = 0.0f;
#pragma unroll
    for (int kh = 0; kh < 3; ++kh)
#pragma unroll
      for (int kw = 0; kw < 3; ++kw)
#pragma unroll
        for (int ci = 0; ci < 3; ++ci) {
          int k = (ci * 3 + kh) * 3 + kw;
          float wv = w1[co * 27 + k];
          acc += (wv < 0.0f) ? -xv[k] : xv[k];
        }
    float yv = acc + b1[co];
    u32 j = ((u32)(n * 128 + co) << 10) | (u32)(y << 5) | (u32)xx;
    bm[h] = __ballot(act_neg(yv, k0, k1, j));
  }
  if (lane == 0) {
    u32* o = out + ((n * 32 + y) * 32 + xx) * 4;
    o[0] = (u32)bm[0];
    o[1] = (u32)(bm[0] >> 32);
    o[2] = (u32)bm[1];
    o[3] = (u32)(bm[1] >> 32);
  }
}

// ---------------------------------------------------------------------------
// Binary conv (layers 2..6) v3 — mechanical restructure of the proven k_bconv:
// identical math (per-tap masks, clamped offsets, 32WV - 2*popc(..&m), same
// RNG indices), new structure: 256-thread block = 4 waves sharing one staged
// tile; wave wv owns channel chunk (z*4+wv)*32; channel loop = runtime outer
// over groups of UN (low VGPR); LDS row stride padded to Wp words so lane-
// consecutive ds_read_b128 are conflict-free (Wp*16B steps through distinct
// 16B slots mod 128B).
// ---------------------------------------------------------------------------
template <int W, int Wp, int UN>
__global__ __launch_bounds__(256, 4) void k_bconv3(
    const u32* __restrict__ in, const u32* __restrict__ pw,
    const float* __restrict__ bias, int Cout, u32 k0, u32 k1,
    u32* __restrict__ out) {
  const int tid = threadIdx.x;
  const int lane = tid & 63;
  const int wv = __builtin_amdgcn_readfirstlane(tid >> 6);
  const int xx = lane & 31, yo = lane >> 5;
  const int n = blockIdx.x;
  const int yb = blockIdx.y;
  const int c0 = (blockIdx.z * 4 + wv) * 32;
  const int y = yb * 2 + yo;
  const int WOUT = Cout >> 5;

  __shared__ __align__(16) u32 tile[4 * 32 * Wp];  // rows yb*2-1 .. yb*2+2

  for (int idx = tid; idx < 4 * 32 * W; idx += 256) {
    int wi = idx & (W - 1);
    int xi = (idx / W) & 31;
    int r = idx / (W * 32);
    int gy = yb * 2 - 1 + r;
    if ((unsigned)gy < 32u)
      tile[(r * 32 + xi) * Wp + wi] = in[((n * 32 + gy) * 32 + xi) * W + wi];
  }
  __syncthreads();

  u32 mask[9];
  int toff[9];
  int V = 0;
#pragma unroll
  for (int t = 0; t < 9; ++t) {
    int dy = t / 3 - 1, dx = t % 3 - 1;
    int gy = y + dy, gx = xx + dx;
    bool valid = ((unsigned)gy < 32u) && ((unsigned)gx < 32u);
    mask[t] = valid ? 0xffffffffu : 0u;
    V += valid ? 1 : 0;
    int r = yo + dy + 1;
    int xc = gx < 0 ? 0 : (gx > 31 ? 31 : gx);
    toff[t] = (r * 32 + xc) * Wp;
  }

  const u32* tf = &tile[0];
  const u32 jbase = ((u32)(n * Cout) << 10) | (u32)(y << 5) | (u32)xx;
  const u32 outoff = (u32)(((n * 32 + y) * 32 + xx) * WOUT);

  u32 packed = 0;
#pragma unroll 1
  for (int cg = 0; cg < 32 / UN; ++cg) {
    int acc[UN];
#pragma unroll
    for (int u = 0; u < UN; ++u) acc[u] = 0;

#pragma unroll
    for (int t = 0; t < 9; ++t) {
      const u32 m = mask[t];
      u32 A[W];
      const u32* src = tf + toff[t];
#pragma unroll
      for (int q4 = 0; q4 < W / 4; ++q4) {
        uint4 av = *(const uint4*)(src + q4 * 4);
        A[q4 * 4 + 0] = av.x; A[q4 * 4 + 1] = av.y;
        A[q4 * 4 + 2] = av.z; A[q4 * 4 + 3] = av.w;
      }
#pragma unroll
      for (int u = 0; u < UN; ++u) {
        const uint4* wr =
            (const uint4*)(pw + (((size_t)(c0 + cg * UN + u)) * 9 + t) * W);
#pragma unroll
        for (int q4 = 0; q4 < W / 4; ++q4) {
          uint4 w4 = wr[q4];
          acc[u] += __popc((A[q4 * 4 + 0] ^ w4.x) & m) +
                    __popc((A[q4 * 4 + 1] ^ w4.y) & m) +
                    __popc((A[q4 * 4 + 2] ^ w4.z) & m) +
                    __popc((A[q4 * 4 + 3] ^ w4.w) & m);
        }
      }
    }

#pragma unroll
    for (int u = 0; u < UN; ++u) {
      const int c = c0 + cg * UN + u;
      float yv = (float)(32 * W * V - 2 * acc[u]) + bias[c];
      bool neg = act_neg(yv, k0, k1, jbase + ((u32)c << 10));
      packed |= (neg ? 1u : 0u) << (c & 31);
    }
  }
  out[outoff + (u32)(c0 >> 5)] = packed;
}

// ---------------------------------------------------------------------------
// Repack conv6 output (channel-packed) into FC1 row layout (x-packed).
// ---------------------------------------------------------------------------
__global__ void k_repack(const u32* __restrict__ a6, u32* __restrict__ f0) {
  int idx = blockIdx.x * blockDim.x + threadIdx.x;
  if (idx >= 4096 * 256) return;
  int w = idx & 255, r = idx >> 8;
  int n = r >> 6, chi = r & 63;
  int clo = w >> 5, yy = w & 31;
  int c = chi * 8 + clo;
  const u32* base = a6 + (size_t)((n * 32 + yy) * 32) * 16 + (c >> 5);
  u32 sh = (u32)(c & 31);
  u32 word = 0;
#pragma unroll
  for (int xp = 0; xp < 32; ++xp)
    word |= ((base[xp * 16] >> sh) & 1u) << xp;
  f0[idx] = word;
}

// ---------------------------------------------------------------------------
// Binary FC with transposed weights (proven round 4). Block 256 = 4 waves;
// 32 rows (LDS) x 64 outputs; wave handles 8 rows; lane = o.
// ---------------------------------------------------------------------------
template <int KW>
__global__ __launch_bounds__(256, 4) void k_fct(
    const u32* __restrict__ in, const u32* __restrict__ pwT,
    const float* __restrict__ bias, int O, u32 k0, u32 k1,
    u32* __restrict__ out) {
  const int tid = threadIdx.x, lane = tid & 63;
  const int wv = __builtin_amdgcn_readfirstlane(tid >> 6);
  const int rbase = blockIdx.x * 32;
  const int obase = blockIdx.y * 64;
  __shared__ __align__(16) u32 rows[32 * KW];
  for (int i = tid; i < 32 * KW; i += 256)
    rows[i] = in[(size_t)(rbase + i / KW) * KW + (i % KW)];
  __syncthreads();

  const int o = obase + lane;
  const int r0 = wv * 8;
  u32 acc[8];
#pragma unroll
  for (int rr = 0; rr < 8; ++rr) acc[rr] = 0;
  for (int k4 = 0; k4 < KW / 4; ++k4) {
    uint4 w4 = ((const uint4*)pwT)[(size_t)k4 * O + o];
#pragma unroll
    for (int rr = 0; rr < 8; ++rr) {
      uint4 av = *(const uint4*)&rows[(r0 + rr) * KW + k4 * 4];
      acc[rr] += __popc(av.x ^ w4.x) + __popc(av.y ^ w4.y) +
                 __popc(av.z ^ w4.z) + __popc(av.w ^ w4.w);
    }
  }
  const int OW = O >> 5;
  const float bo = bias[o];
#pragma unroll
  for (int rr = 0; rr < 8; ++rr) {
    int r = rbase + r0 + rr;
    float yv = (float)(KW * 32 - 2 * (int)acc[rr]) + bo;
    bool neg = act_neg(yv, k0, k1, (u32)r * (u32)O + (u32)o);
    u64 b = __ballot(neg);
    if (lane == 0) {
      out[(size_t)r * OW + (obase >> 5)] = (u32)b;
      out[(size_t)r * OW + (obase >> 5) + 1] = (u32)(b >> 32);
    }
  }
}

// FC3: [4096][32 words] x [10][32 words] -> fp32 +-1 output [4096][10].
__global__ __launch_bounds__(64) void k_fc3(
    const u32* __restrict__ in, const u32* __restrict__ pw,
    const float* __restrict__ bias, u32 k0, u32 k1,
    float* __restrict__ outp) {
  const int lane = threadIdx.x;
  const int r = blockIdx.x;
  __shared__ u32 row[32];
  if (lane < 32) row[lane] = in[(size_t)r * 32 + lane];
  __syncthreads();
  if (lane < 10) {
    int acc = 0;
#pragma unroll
    for (int k = 0; k < 32; ++k) acc += __popc(row[k] ^ pw[lane * 32 + k]);
    float yv = (float)(1024 - 2 * acc) + bias[lane];
    bool neg = act_neg(yv, k0, k1, (u32)r * 10u + (u32)lane);
    outp[(size_t)r * 10 + lane] = neg ? -1.0f : 1.0f;
  }
}

// ---------------------------------------------------------------------------
extern "C" void kernel_launch(void* const* d_in, const int* in_sizes, int n_in,
                              void* d_out, int out_size, void* d_ws,
                              size_t ws_size, hipStream_t stream) {
  const float* x   = (const float*)d_in[0];
  const float* w1  = (const float*)d_in[1];
  const float* b1  = (const float*)d_in[2];
  const float* w2  = (const float*)d_in[3];
  const float* b2  = (const float*)d_in[4];
  const float* w3  = (const float*)d_in[5];
  const float* b3  = (const float*)d_in[6];
  const float* w4  = (const float*)d_in[7];
  const float* b4  = (const float*)d_in[8];
  const float* w5  = (const float*)d_in[9];
  const float* b5  = (const float*)d_in[10];
  const float* w6  = (const float*)d_in[11];
  const float* b6  = (const float*)d_in[12];
  const float* fw1 = (const float*)d_in[13];
  const float* fb1 = (const float*)d_in[14];
  const float* fw2 = (const float*)d_in[15];
  const float* fb2 = (const float*)d_in[16];
  const float* fw3 = (const float*)d_in[17];
  const float* fb3 = (const float*)d_in[18];

  u32 K[9][2];
  for (int i = 0; i < 9; ++i) tf2x32(0u, 42u, 0u, (u32)i, K[i][0], K[i][1]);

  char* ws = (char*)d_ws;
  size_t off = 0;
  auto alloc = [&](size_t bytes) -> char* {
    char* p = ws + off;
    off += (bytes + 255) & ~(size_t)255;
    return p;
  };
  u32* pw2  = (u32*)alloc(256u * 9 * 4 * 4);
  u32* pw3  = (u32*)alloc(256u * 9 * 8 * 4);
  u32* pw4  = (u32*)alloc(256u * 9 * 8 * 4);
  u32* pw5  = (u32*)alloc(512u * 9 * 8 * 4);
  u32* pw6  = (u32*)alloc(512u * 9 * 16 * 4);
  u32* pfw1 = (u32*)alloc(1024u * 256 * 4);
  u32* pfw2 = (u32*)alloc(1024u * 32 * 4);
  u32* pfw3 = (u32*)alloc(10u * 32 * 4);
  u32* a1   = (u32*)alloc(64u * 1024 * 4 * 4);
  u32* a2   = (u32*)alloc(64u * 1024 * 8 * 4);
  u32* a3   = (u32*)alloc(64u * 1024 * 8 * 4);
  u32* a4   = (u32*)alloc(64u * 1024 * 8 * 4);
  u32* a5   = (u32*)alloc(64u * 1024 * 16 * 4);
  u32* a6   = (u32*)alloc(64u * 1024 * 16 * 4);
  u32* f0   = (u32*)alloc(4096u * 256 * 4);
  u32* f1   = (u32*)alloc(4096u * 32 * 4);
  u32* f2   = (u32*)alloc(4096u * 32 * 4);
  (void)ws_size;  // ~23 MB of workspace

  int t;
  t = 256 * 9 * 4;
  k_pack_convw<<<(t + 255) / 256, 256, 0, stream>>>(w2, pw2, 256, 128);
  t = 256 * 9 * 8;
  k_pack_convw<<<(t + 255) / 256, 256, 0, stream>>>(w3, pw3, 256, 256);
  k_pack_convw<<<(t + 255) / 256, 256, 0, stream>>>(w4, pw4, 256, 256);
  t = 512 * 9 * 8;
  k_pack_convw<<<(t + 255) / 256, 256, 0, stream>>>(w5, pw5, 512, 256);
  t = 512 * 9 * 16;
  k_pack_convw<<<(t + 255) / 256, 256, 0, stream>>>(w6, pw6, 512, 512);
  t = 1024 * 256;
  k_pack_fcwT<<<(t + 255) / 256, 256, 0, stream>>>(fw1, pfw1, 1024, 8192);
  t = 1024 * 32;
  k_pack_fcwT<<<(t + 255) / 256, 256, 0, stream>>>(fw2, pfw2, 1024, 1024);
  t = 10 * 32;
  k_pack_fcw<<<(t + 255) / 256, 256, 0, stream>>>(fw3, pfw3, 10, 1024);

  k_conv1<<<16384, 256, 0, stream>>>(x, w1, b1, K[0][0], K[0][1], a1);
  k_bconv3<4, 4, 8><<<dim3(64, 16, 2), 256, 0, stream>>>(
      a1, pw2, b2, 256, K[1][0], K[1][1], a2);
  k_bconv3<8, 12, 8><<<dim3(64, 16, 2), 256, 0, stream>>>(
      a2, pw3, b3, 256, K[2][0], K[2][1], a3);
  k_bconv3<8, 12, 8><<<dim3(64, 16, 2), 256, 0, stream>>>(
      a3, pw4, b4, 256, K[3][0], K[3][1], a4);
  k_bconv3<8, 12, 8><<<dim3(64, 16, 4), 256, 0, stream>>>(
      a4, pw5, b5, 512, K[4][0], K[4][1], a5);
  k_bconv3<16, 20, 4><<<dim3(64, 16, 4), 256, 0, stream>>>(
      a5, pw6, b6, 512, K[5][0], K[5][1], a6);
  k_repack<<<(4096 * 256 + 255) / 256, 256, 0, stream>>>(a6, f0);
  k_fct<256><<<dim3(128, 16), 256, 0, stream>>>(f0, pfw1, fb1, 1024,
                                                K[6][0], K[6][1], f1);
  k_fct<32><<<dim3(128, 16), 256, 0, stream>>>(f1, pfw2, fb2, 1024,
                                               K[7][0], K[7][1], f2);
  k_fc3<<<4096, 64, 0, stream>>>(f2, pfw3, fb3, K[8][0], K[8][1],
                                 (float*)d_out);
}

// Round 6
// 2165.060 us; speedup vs baseline: 5.9674x; 5.9674x over previous
//
#include <hip/hip_runtime.h>
#include <stdint.h>

typedef unsigned int u32;
typedef unsigned long long u64;

// ---------------------------------------------------------------------------
// Threefry-2x32, 20 rounds — bit-exact replica of JAX's threefry2x32 primitive.
// ---------------------------------------------------------------------------
__host__ __device__ __forceinline__ void tf2x32(u32 k0, u32 k1, u32 x0, u32 x1,
                                                u32& o0, u32& o1) {
  u32 k2 = k0 ^ k1 ^ 0x1BD11BDAu;
  x0 += k0; x1 += k1;
#define TFR(r) { x0 += x1; x1 = (x1 << (r)) | (x1 >> (32 - (r))); x1 ^= x0; }
  TFR(13) TFR(15) TFR(26) TFR(6)   x0 += k1; x1 += k2 + 1u;
  TFR(17) TFR(29) TFR(16) TFR(24)  x0 += k2; x1 += k0 + 2u;
  TFR(13) TFR(15) TFR(26) TFR(6)   x0 += k0; x1 += k1 + 3u;
  TFR(17) TFR(29) TFR(16) TFR(24)  x0 += k1; x1 += k2 + 4u;
  TFR(13) TFR(15) TFR(26) TFR(6)   x0 += k2; x1 += k0 + 5u;
#undef TFR
  o0 = x0; o1 = x1;
}

// stoch_act: p = clip((y+1)*0.5, 0, 1); u from partitionable random bits of
// flat index j: bits = o0 ^ o1 of TF(key, (0, j)). Returns true if out = -1.
__device__ __forceinline__ bool act_neg(float y, u32 k0, u32 k1, u32 j) {
  u32 o0, o1;
  tf2x32(k0, k1, 0u, j, o0, o1);
  u32 bits = o0 ^ o1;
  float u = __uint_as_float(0x3f800000u | (bits >> 9)) - 1.0f;
  float t = (y + 1.0f) * 0.5f;
  float p = fminf(fmaxf(t, 0.0f), 1.0f);
  return !(u < p);
}

// ---------------------------------------------------------------------------
// Weight packing (bit = 1 iff weight < 0). Conv: [C][Cin][3][3] -> [C][9][W].
// ---------------------------------------------------------------------------
__global__ void k_pack_convw(const float* __restrict__ w, u32* __restrict__ pw,
                             int Cout, int Cin) {
  int Wi = Cin >> 5;
  int idx = blockIdx.x * blockDim.x + threadIdx.x;
  int total = Cout * 9 * Wi;
  if (idx >= total) return;
  int wi = idx % Wi;
  int t = (idx / Wi) % 9;
  int co = idx / (Wi * 9);
  int kh = t / 3, kw = t % 3;
  u32 word = 0;
  for (int b = 0; b < 32; ++b) {
    int ci = wi * 32 + b;
    float v = w[((co * Cin + ci) * 3 + kh) * 3 + kw];
    word |= (v < 0.0f ? 1u : 0u) << b;
  }
  pw[idx] = word;
}

// FC weight pack, transposed for coalesced lane=o loads: pwT[k4][o][j].
__global__ void k_pack_fcwT(const float* __restrict__ w, u32* __restrict__ pwT,
                            int O, int K) {
  int KW = K >> 5;
  int idx = blockIdx.x * blockDim.x + threadIdx.x;
  if (idx >= O * KW) return;
  int kw = idx % KW, o = idx / KW;
  u32 word = 0;
  for (int b = 0; b < 32; ++b)
    word |= (w[(size_t)o * K + kw * 32 + b] < 0.0f ? 1u : 0u) << b;
  int k4 = kw >> 2, j = kw & 3;
  pwT[((size_t)k4 * O + o) * 4 + j] = word;
}

// FC weight pack, row-major (fc3).
__global__ void k_pack_fcw(const float* __restrict__ w, u32* __restrict__ pw,
                           int O, int K) {
  int KW = K >> 5;
  int idx = blockIdx.x * blockDim.x + threadIdx.x;
  if (idx >= O * KW) return;
  int kw = idx % KW, o = idx / KW;
  u32 word = 0;
  for (int b = 0; b < 32; ++b)
    word |= (w[o * K + kw * 32 + b] < 0.0f ? 1u : 0u) << b;
  pw[idx] = word;
}

// ---------------------------------------------------------------------------
// conv1: fp32 x [64][3][32][32], binarized w1, +b1, stoch_act key0.
// Output PLANAR packed: a1[(n*4 + w)*1024 + y*32 + x]. One wave per (n,y,x).
// ---------------------------------------------------------------------------
__global__ __launch_bounds__(256) void k_conv1(
    const float* __restrict__ x, const float* __restrict__ w1,
    const float* __restrict__ b1, u32 k0, u32 k1, u32* __restrict__ out) {
  int wave = (blockIdx.x * 256 + threadIdx.x) >> 6;
  int lane = threadIdx.x & 63;
  int n = wave >> 10;
  int rem = wave & 1023;
  int y = rem >> 5, xx = rem & 31;

  float xv[27];
#pragma unroll
  for (int ci = 0; ci < 3; ++ci)
#pragma unroll
    for (int dy = -1; dy <= 1; ++dy)
#pragma unroll
      for (int dx = -1; dx <= 1; ++dx) {
        int gy = y + dy, gx = xx + dx;
        float v = 0.0f;
        if ((unsigned)gy < 32u && (unsigned)gx < 32u)
          v = x[((n * 3 + ci) * 32 + gy) * 32 + gx];
        xv[(ci * 3 + (dy + 1)) * 3 + (dx + 1)] = v;
      }

  u64 bm[2];
#pragma unroll
  for (int h = 0; h < 2; ++h) {
    int co = lane + h * 64;
    float acc = 0.0f;
#pragma unroll
    for (int kh = 0; kh < 3; ++kh)
#pragma unroll
      for (int kw = 0; kw < 3; ++kw)
#pragma unroll
        for (int ci = 0; ci < 3; ++ci) {
          int k = (ci * 3 + kh) * 3 + kw;
          float wv = w1[co * 27 + k];
          acc += (wv < 0.0f) ? -xv[k] : xv[k];
        }
    float yv = acc + b1[co];
    u32 j = ((u32)(n * 128 + co) << 10) | (u32)(y << 5) | (u32)xx;
    bm[h] = __ballot(act_neg(yv, k0, k1, j));
  }
  // ballot results are wave-uniform: lanes 0..3 write the 4 planar words.
  if (lane < 4) {
    u32 wsel = (lane & 1) ? (u32)(bm[lane >> 1] >> 32) : (u32)bm[lane >> 1];
    out[(u32)(n * 4 + lane) * 1024u + (u32)(y * 32 + xx)] = wsel;
  }
}

// ---------------------------------------------------------------------------
// Binary conv (layers 2..6) v4 — same math as the PROVEN r2/r5 kernels
// (per-tap masks, clamped x offsets, 32WV - 2*popc(..&m), same RNG indices),
// restructured so the inner loop touches NO global memory:
//  - planar activations in/out: [(n*W + w)*1024 + y*32 + x]
//  - block = 256 threads = 16 rows x 32 x, one 32-channel chunk (grid z)
//  - chunk weights (32*9*W words) + biases staged coalesced into LDS once
//  - activation tile at[w][18 rows][32 x] in LDS, bank = x (conflict-free);
//    weight reads are uniform broadcasts (conflict-free)
//  - output writes 1KB-dense per block
// ---------------------------------------------------------------------------
template <int W>
__global__ __launch_bounds__(256, 2) void k_bconv4(
    const u32* __restrict__ in, const u32* __restrict__ pw,
    const float* __restrict__ bias, int Cout, u32 k0, u32 k1,
    u32* __restrict__ out) {
  const int tid = threadIdx.x;
  const int xx = tid & 31, yl = tid >> 5;  // yl in 0..7
  const int n = blockIdx.x;
  const int y0 = blockIdx.y * 16;
  const int z = blockIdx.z;
  const int c0 = z * 32;
  const int WOUT = Cout >> 5;

  __shared__ __align__(16) u32 wt[32 * 9 * W];
  __shared__ u32 at[W * 18 * 32];
  __shared__ float bb[32];

  // Stage chunk weights (coalesced; contiguous in pw).
  for (int i = tid; i < 32 * 9 * W; i += 256) wt[i] = pw[(size_t)c0 * 9 * W + i];
  if (tid < 32) bb[tid] = bias[c0 + tid];
  // Stage activation rows y0-1 .. y0+16 (18 rows), planar, zeros OOB.
  for (int i = tid; i < W * 18 * 32; i += 256) {
    int xi = i & 31;
    int r = (i >> 5) % 18;
    int wi = i / (18 * 32);
    int gy = y0 - 1 + r;
    u32 v = 0;
    if ((unsigned)gy < 32u) v = in[(u32)(n * W + wi) * 1024u + (u32)(gy * 32 + xi)];
    at[(wi * 18 + r) * 32 + xi] = v;
  }
  __syncthreads();

#pragma unroll
  for (int py = 0; py < 2; ++py) {
    const int y = y0 + py * 8 + yl;
    // Per-pixel tap validity (identical math to the proven kernel).
    u32 mask[9];
    int rowi[9], xci[9];
    int V = 0;
#pragma unroll
    for (int t = 0; t < 9; ++t) {
      int dy = t / 3 - 1, dx = t % 3 - 1;
      int gy = y + dy, gx = xx + dx;
      bool valid = ((unsigned)gy < 32u) && ((unsigned)gx < 32u);
      mask[t] = valid ? 0xffffffffu : 0u;
      V += valid ? 1 : 0;
      rowi[t] = py * 8 + yl + dy + 1;               // row in at (0..17)
      xci[t] = gx < 0 ? 0 : (gx > 31 ? 31 : gx);    // clamped x
    }
    const int base = 32 * W * V;
    const u32 jbase = ((u32)(n * Cout + c0) << 10) | (u32)(y * 32 + xx);

    u32 packed = 0;
#pragma unroll 1
    for (int cg = 0; cg < 8; ++cg) {
      int acc[4];
#pragma unroll
      for (int u = 0; u < 4; ++u) acc[u] = 0;

#pragma unroll
      for (int t = 0; t < 9; ++t) {
        const u32 m = mask[t];
        u32 A[W];
#pragma unroll
        for (int wi = 0; wi < W; ++wi)
          A[wi] = at[(wi * 18 + rowi[t]) * 32 + xci[t]];
#pragma unroll
        for (int u = 0; u < 4; ++u) {
          const u32* wr = &wt[((cg * 4 + u) * 9 + t) * W];
#pragma unroll
          for (int q4 = 0; q4 < W / 4; ++q4) {
            uint4 w4 = *(const uint4*)(wr + q4 * 4);
            acc[u] += __popc((A[q4 * 4 + 0] ^ w4.x) & m) +
                      __popc((A[q4 * 4 + 1] ^ w4.y) & m) +
                      __popc((A[q4 * 4 + 2] ^ w4.z) & m) +
                      __popc((A[q4 * 4 + 3] ^ w4.w) & m);
          }
        }
      }

#pragma unroll
      for (int u = 0; u < 4; ++u) {
        const int cl = cg * 4 + u;  // channel within chunk
        float yv = (float)(base - 2 * acc[u]) + bb[cl];
        bool neg = act_neg(yv, k0, k1, jbase + ((u32)cl << 10));
        packed |= (neg ? 1u : 0u) << cl;
      }
    }
    out[(u32)(n * WOUT + z) * 1024u + (u32)(y * 32 + xx)] = packed;
  }
}

// ---------------------------------------------------------------------------
// Repack conv6 PLANAR output into FC1 row layout (x-packed):
// f0 row r = n*64 + c_hi, word w: c_lo = w/32, y = w%32, bits = x 0..31,
// channel c = c_hi*8 + c_lo. Reads 32 consecutive words (dense).
// ---------------------------------------------------------------------------
__global__ void k_repack(const u32* __restrict__ a6, u32* __restrict__ f0) {
  int idx = blockIdx.x * blockDim.x + threadIdx.x;
  if (idx >= 4096 * 256) return;
  int w = idx & 255, r = idx >> 8;
  int n = r >> 6, chi = r & 63;
  int clo = w >> 5, yy = w & 31;
  int c = chi * 8 + clo;
  const u32* base = a6 + (u32)(n * 16 + (c >> 5)) * 1024u + (u32)(yy * 32);
  u32 sh = (u32)(c & 31);
  u32 word = 0;
#pragma unroll
  for (int xp = 0; xp < 32; ++xp)
    word |= ((base[xp] >> sh) & 1u) << xp;
  f0[idx] = word;
}

// ---------------------------------------------------------------------------
// Binary FC with transposed weights (proven round 4). Block 256 = 4 waves;
// 32 rows (LDS) x 64 outputs; wave handles 8 rows; lane = o.
// ---------------------------------------------------------------------------
template <int KW>
__global__ __launch_bounds__(256, 4) void k_fct(
    const u32* __restrict__ in, const u32* __restrict__ pwT,
    const float* __restrict__ bias, int O, u32 k0, u32 k1,
    u32* __restrict__ out) {
  const int tid = threadIdx.x, lane = tid & 63;
  const int wv = __builtin_amdgcn_readfirstlane(tid >> 6);
  const int rbase = blockIdx.x * 32;
  const int obase = blockIdx.y * 64;
  __shared__ __align__(16) u32 rows[32 * KW];
  for (int i = tid; i < 32 * KW; i += 256)
    rows[i] = in[(size_t)(rbase + i / KW) * KW + (i % KW)];
  __syncthreads();

  const int o = obase + lane;
  const int r0 = wv * 8;
  u32 acc[8];
#pragma unroll
  for (int rr = 0; rr < 8; ++rr) acc[rr] = 0;
  for (int k4 = 0; k4 < KW / 4; ++k4) {
    uint4 w4 = ((const uint4*)pwT)[(size_t)k4 * O + o];
#pragma unroll
    for (int rr = 0; rr < 8; ++rr) {
      uint4 av = *(const uint4*)&rows[(r0 + rr) * KW + k4 * 4];
      acc[rr] += __popc(av.x ^ w4.x) + __popc(av.y ^ w4.y) +
                 __popc(av.z ^ w4.z) + __popc(av.w ^ w4.w);
    }
  }
  const int OW = O >> 5;
  const float bo = bias[o];
#pragma unroll
  for (int rr = 0; rr < 8; ++rr) {
    int r = rbase + r0 + rr;
    float yv = (float)(KW * 32 - 2 * (int)acc[rr]) + bo;
    bool neg = act_neg(yv, k0, k1, (u32)r * (u32)O + (u32)o);
    u64 b = __ballot(neg);
    if (lane == 0) {
      out[(size_t)r * OW + (obase >> 5)] = (u32)b;
      out[(size_t)r * OW + (obase >> 5) + 1] = (u32)(b >> 32);
    }
  }
}

// FC3: [4096][32 words] x [10][32 words] -> fp32 +-1 output [4096][10].
__global__ __launch_bounds__(64) void k_fc3(
    const u32* __restrict__ in, const u32* __restrict__ pw,
    const float* __restrict__ bias, u32 k0, u32 k1,
    float* __restrict__ outp) {
  const int lane = threadIdx.x;
  const int r = blockIdx.x;
  __shared__ u32 row[32];
  if (lane < 32) row[lane] = in[(size_t)r * 32 + lane];
  __syncthreads();
  if (lane < 10) {
    int acc = 0;
#pragma unroll
    for (int k = 0; k < 32; ++k) acc += __popc(row[k] ^ pw[lane * 32 + k]);
    float yv = (float)(1024 - 2 * acc) + bias[lane];
    bool neg = act_neg(yv, k0, k1, (u32)r * 10u + (u32)lane);
    outp[(size_t)r * 10 + lane] = neg ? -1.0f : 1.0f;
  }
}

// ---------------------------------------------------------------------------
extern "C" void kernel_launch(void* const* d_in, const int* in_sizes, int n_in,
                              void* d_out, int out_size, void* d_ws,
                              size_t ws_size, hipStream_t stream) {
  const float* x   = (const float*)d_in[0];
  const float* w1  = (const float*)d_in[1];
  const float* b1  = (const float*)d_in[2];
  const float* w2  = (const float*)d_in[3];
  const float* b2  = (const float*)d_in[4];
  const float* w3  = (const float*)d_in[5];
  const float* b3  = (const float*)d_in[6];
  const float* w4  = (const float*)d_in[7];
  const float* b4  = (const float*)d_in[8];
  const float* w5  = (const float*)d_in[9];
  const float* b5  = (const float*)d_in[10];
  const float* w6  = (const float*)d_in[11];
  const float* b6  = (const float*)d_in[12];
  const float* fw1 = (const float*)d_in[13];
  const float* fb1 = (const float*)d_in[14];
  const float* fw2 = (const float*)d_in[15];
  const float* fb2 = (const float*)d_in[16];
  const float* fw3 = (const float*)d_in[17];
  const float* fb3 = (const float*)d_in[18];

  u32 K[9][2];
  for (int i = 0; i < 9; ++i) tf2x32(0u, 42u, 0u, (u32)i, K[i][0], K[i][1]);

  char* ws = (char*)d_ws;
  size_t off = 0;
  auto alloc = [&](size_t bytes) -> char* {
    char* p = ws + off;
    off += (bytes + 255) & ~(size_t)255;
    return p;
  };
  u32* pw2  = (u32*)alloc(256u * 9 * 4 * 4);
  u32* pw3  = (u32*)alloc(256u * 9 * 8 * 4);
  u32* pw4  = (u32*)alloc(256u * 9 * 8 * 4);
  u32* pw5  = (u32*)alloc(512u * 9 * 8 * 4);
  u32* pw6  = (u32*)alloc(512u * 9 * 16 * 4);
  u32* pfw1 = (u32*)alloc(1024u * 256 * 4);
  u32* pfw2 = (u32*)alloc(1024u * 32 * 4);
  u32* pfw3 = (u32*)alloc(10u * 32 * 4);
  u32* a1   = (u32*)alloc(64u * 1024 * 4 * 4);
  u32* a2   = (u32*)alloc(64u * 1024 * 8 * 4);
  u32* a3   = (u32*)alloc(64u * 1024 * 8 * 4);
  u32* a4   = (u32*)alloc(64u * 1024 * 8 * 4);
  u32* a5   = (u32*)alloc(64u * 1024 * 16 * 4);
  u32* a6   = (u32*)alloc(64u * 1024 * 16 * 4);
  u32* f0   = (u32*)alloc(4096u * 256 * 4);
  u32* f1   = (u32*)alloc(4096u * 32 * 4);
  u32* f2   = (u32*)alloc(4096u * 32 * 4);
  (void)ws_size;  // ~23 MB of workspace

  int t;
  t = 256 * 9 * 4;
  k_pack_convw<<<(t + 255) / 256, 256, 0, stream>>>(w2, pw2, 256, 128);
  t = 256 * 9 * 8;
  k_pack_convw<<<(t + 255) / 256, 256, 0, stream>>>(w3, pw3, 256, 256);
  k_pack_convw<<<(t + 255) / 256, 256, 0, stream>>>(w4, pw4, 256, 256);
  t = 512 * 9 * 8;
  k_pack_convw<<<(t + 255) / 256, 256, 0, stream>>>(w5, pw5, 512, 256);
  t = 512 * 9 * 16;
  k_pack_convw<<<(t + 255) / 256, 256, 0, stream>>>(w6, pw6, 512, 512);
  t = 1024 * 256;
  k_pack_fcwT<<<(t + 255) / 256, 256, 0, stream>>>(fw1, pfw1, 1024, 8192);
  t = 1024 * 32;
  k_pack_fcwT<<<(t + 255) / 256, 256, 0, stream>>>(fw2, pfw2, 1024, 1024);
  t = 10 * 32;
  k_pack_fcw<<<(t + 255) / 256, 256, 0, stream>>>(fw3, pfw3, 10, 1024);

  k_conv1<<<16384, 256, 0, stream>>>(x, w1, b1, K[0][0], K[0][1], a1);
  k_bconv4<4><<<dim3(64, 2, 8), 256, 0, stream>>>(a1, pw2, b2, 256,
                                                  K[1][0], K[1][1], a2);
  k_bconv4<8><<<dim3(64, 2, 8), 256, 0, stream>>>(a2, pw3, b3, 256,
                                                  K[2][0], K[2][1], a3);
  k_bconv4<8><<<dim3(64, 2, 8), 256, 0, stream>>>(a3, pw4, b4, 256,
                                                  K[3][0], K[3][1], a4);
  k_bconv4<8><<<dim3(64, 2, 16), 256, 0, stream>>>(a4, pw5, b5, 512,
                                                   K[4][0], K[4][1], a5);
  k_bconv4<16><<<dim3(64, 2, 16), 256, 0, stream>>>(a5, pw6, b6, 512,
                                                    K[5][0], K[5][1], a6);
  k_repack<<<(4096 * 256 + 255) / 256, 256, 0, stream>>>(a6, f0);
  k_fct<256><<<dim3(128, 16), 256, 0, stream>>>(f0, pfw1, fb1, 1024,
                                                K[6][0], K[6][1], f1);
  k_fct<32><<<dim3(128, 16), 256, 0, stream>>>(f1, pfw2, fb2, 1024,
                                               K[7][0], K[7][1], f2);
  k_fc3<<<4096, 64, 0, stream>>>(f2, pfw3, fb3, K[8][0], K[8][1],
                                 (float*)d_out);
}

// Round 7
// 1306.844 us; speedup vs baseline: 9.8863x; 1.6567x over previous
//
#include <hip/hip_runtime.h>
#include <stdint.h>

typedef unsigned int u32;
typedef unsigned long long u64;

// ---------------------------------------------------------------------------
// Threefry-2x32, 20 rounds — bit-exact replica of JAX's threefry2x32 primitive.
// ---------------------------------------------------------------------------
__host__ __device__ __forceinline__ void tf2x32(u32 k0, u32 k1, u32 x0, u32 x1,
                                                u32& o0, u32& o1) {
  u32 k2 = k0 ^ k1 ^ 0x1BD11BDAu;
  x0 += k0; x1 += k1;
#define TFR(r) { x0 += x1; x1 = (x1 << (r)) | (x1 >> (32 - (r))); x1 ^= x0; }
  TFR(13) TFR(15) TFR(26) TFR(6)   x0 += k1; x1 += k2 + 1u;
  TFR(17) TFR(29) TFR(16) TFR(24)  x0 += k2; x1 += k0 + 2u;
  TFR(13) TFR(15) TFR(26) TFR(6)   x0 += k0; x1 += k1 + 3u;
  TFR(17) TFR(29) TFR(16) TFR(24)  x0 += k1; x1 += k2 + 4u;
  TFR(13) TFR(15) TFR(26) TFR(6)   x0 += k2; x1 += k0 + 5u;
#undef TFR
  o0 = x0; o1 = x1;
}

// stoch_act: p = clip((y+1)*0.5, 0, 1); u from partitionable random bits of
// flat index j: bits = o0 ^ o1 of TF(key, (0, j)). Returns true if out = -1.
__device__ __forceinline__ bool act_neg(float y, u32 k0, u32 k1, u32 j) {
  u32 o0, o1;
  tf2x32(k0, k1, 0u, j, o0, o1);
  u32 bits = o0 ^ o1;
  float u = __uint_as_float(0x3f800000u | (bits >> 9)) - 1.0f;
  float t = (y + 1.0f) * 0.5f;
  float p = fminf(fmaxf(t, 0.0f), 1.0f);
  return !(u < p);
}

// ---------------------------------------------------------------------------
// Weight packing (bit = 1 iff weight < 0). Conv: [C][Cin][3][3] -> [C][9][W].
// ---------------------------------------------------------------------------
__global__ void k_pack_convw(const float* __restrict__ w, u32* __restrict__ pw,
                             int Cout, int Cin) {
  int Wi = Cin >> 5;
  int idx = blockIdx.x * blockDim.x + threadIdx.x;
  int total = Cout * 9 * Wi;
  if (idx >= total) return;
  int wi = idx % Wi;
  int t = (idx / Wi) % 9;
  int co = idx / (Wi * 9);
  int kh = t / 3, kw = t % 3;
  u32 word = 0;
  for (int b = 0; b < 32; ++b) {
    int ci = wi * 32 + b;
    float v = w[((co * Cin + ci) * 3 + kh) * 3 + kw];
    word |= (v < 0.0f ? 1u : 0u) << b;
  }
  pw[idx] = word;
}

// FC weight pack, transposed for coalesced lane=o loads: pwT[k4][o][j].
__global__ void k_pack_fcwT(const float* __restrict__ w, u32* __restrict__ pwT,
                            int O, int K) {
  int KW = K >> 5;
  int idx = blockIdx.x * blockDim.x + threadIdx.x;
  if (idx >= O * KW) return;
  int kw = idx % KW, o = idx / KW;
  u32 word = 0;
  for (int b = 0; b < 32; ++b)
    word |= (w[(size_t)o * K + kw * 32 + b] < 0.0f ? 1u : 0u) << b;
  int k4 = kw >> 2, j = kw & 3;
  pwT[((size_t)k4 * O + o) * 4 + j] = word;
}

// FC weight pack, row-major (fc3).
__global__ void k_pack_fcw(const float* __restrict__ w, u32* __restrict__ pw,
                           int O, int K) {
  int KW = K >> 5;
  int idx = blockIdx.x * blockDim.x + threadIdx.x;
  if (idx >= O * KW) return;
  int kw = idx % KW, o = idx / KW;
  u32 word = 0;
  for (int b = 0; b < 32; ++b)
    word |= (w[o * K + kw * 32 + b] < 0.0f ? 1u : 0u) << b;
  pw[idx] = word;
}

// ---------------------------------------------------------------------------
// conv1: fp32 x [64][3][32][32], binarized w1, +b1, stoch_act key0.
// Output PLANAR packed: a1[(n*4 + w)*1024 + y*32 + x]. One wave per (n,y,x).
// ---------------------------------------------------------------------------
__global__ __launch_bounds__(256) void k_conv1(
    const float* __restrict__ x, const float* __restrict__ w1,
    const float* __restrict__ b1, u32 k0, u32 k1, u32* __restrict__ out) {
  int wave = (blockIdx.x * 256 + threadIdx.x) >> 6;
  int lane = threadIdx.x & 63;
  int n = wave >> 10;
  int rem = wave & 1023;
  int y = rem >> 5, xx = rem & 31;

  float xv[27];
#pragma unroll
  for (int ci = 0; ci < 3; ++ci)
#pragma unroll
    for (int dy = -1; dy <= 1; ++dy)
#pragma unroll
      for (int dx = -1; dx <= 1; ++dx) {
        int gy = y + dy, gx = xx + dx;
        float v = 0.0f;
        if ((unsigned)gy < 32u && (unsigned)gx < 32u)
          v = x[((n * 3 + ci) * 32 + gy) * 32 + gx];
        xv[(ci * 3 + (dy + 1)) * 3 + (dx + 1)] = v;
      }

  u64 bm[2];
#pragma unroll
  for (int h = 0; h < 2; ++h) {
    int co = lane + h * 64;
    float acc = 0.0f;
#pragma unroll
    for (int kh = 0; kh < 3; ++kh)
#pragma unroll
      for (int kw = 0; kw < 3; ++kw)
#pragma unroll
        for (int ci = 0; ci < 3; ++ci) {
          int k = (ci * 3 + kh) * 3 + kw;
          float wv = w1[co * 27 + k];
          acc += (wv < 0.0f) ? -xv[k] : xv[k];
        }
    float yv = acc + b1[co];
    u32 j = ((u32)(n * 128 + co) << 10) | (u32)(y << 5) | (u32)xx;
    bm[h] = __ballot(act_neg(yv, k0, k1, j));
  }
  if (lane < 4) {
    u32 wsel = (lane & 1) ? (u32)(bm[lane >> 1] >> 32) : (u32)bm[lane >> 1];
    out[(u32)(n * 4 + lane) * 1024u + (u32)(y * 32 + xx)] = wsel;
  }
}

// ---------------------------------------------------------------------------
// Binary conv (layers 2..6) v5 — math identical to the PROVEN r6 kernel
// (per-tap masks, clamped x offsets, 32WV - 2*popc(..&m), same RNG indices).
// Structure: block = 256 threads = 8 rows x 32 x, one 32-channel chunk (z).
//  - activations staged planar in LDS (10 rows incl. halo), bank = x
//  - A[W] loaded ONCE per tap (taps = runtime loop), reused by all 32 channels
//  - acc[32] fully static-indexed (channel loop fully unrolled)
//  - weights read at wave-uniform global addresses -> scalar s_load path,
//    zero LDS traffic for weights
// ---------------------------------------------------------------------------
template <int W>
__global__ __launch_bounds__(256, 4) void k_bconv5(
    const u32* __restrict__ in, const u32* __restrict__ pw,
    const float* __restrict__ bias, int Cout, u32 k0, u32 k1,
    u32* __restrict__ out) {
  const int tid = threadIdx.x;
  const int xx = tid & 31, yl = tid >> 5;  // yl in 0..7
  const int n = blockIdx.x;
  const int y0 = blockIdx.y * 8;
  const int z = blockIdx.z;
  const int c0 = z * 32;
  const int WOUT = Cout >> 5;

  __shared__ u32 at[W * 10 * 32];

  // Stage rows y0-1 .. y0+8 (10 rows), planar, zeros OOB.
  for (int i = tid; i < W * 10 * 32; i += 256) {
    int xi = i & 31;
    int r = (i >> 5) % 10;
    int wi = i / (10 * 32);
    int gy = y0 - 1 + r;
    u32 v = 0;
    if ((unsigned)gy < 32u)
      v = in[(u32)(n * W + wi) * 1024u + (u32)(gy * 32 + xi)];
    at[(wi * 10 + r) * 32 + xi] = v;
  }
  __syncthreads();

  const int y = y0 + yl;
  int acc[32];
#pragma unroll
  for (int c = 0; c < 32; ++c) acc[c] = 0;

  int V = 0;
  const u32* pwc0 = pw + (size_t)c0 * 9 * W;  // uniform chunk base

#pragma unroll 1
  for (int ty = 0; ty < 3; ++ty) {
#pragma unroll 1
    for (int tx = 0; tx < 3; ++tx) {
      const int dy = ty - 1, dx = tx - 1;
      const int gy = y + dy, gx = xx + dx;
      const bool valid = ((unsigned)gy < 32u) && ((unsigned)gx < 32u);
      const u32 m = valid ? 0xffffffffu : 0u;
      V += valid ? 1 : 0;
      const int rowi = yl + dy + 1;                    // 0..9
      const int xci = gx < 0 ? 0 : (gx > 31 ? 31 : gx);

      u32 A[W];
      const u32* ap = &at[rowi * 32 + xci];
#pragma unroll
      for (int wi = 0; wi < W; ++wi) A[wi] = ap[wi * 10 * 32];

      const u32* pwt = pwc0 + (ty * 3 + tx) * W;       // uniform
#pragma unroll
      for (int c = 0; c < 32; ++c) {
        const uint4* wr = (const uint4*)(pwt + (size_t)c * 9 * W);
#pragma unroll
        for (int q4 = 0; q4 < W / 4; ++q4) {
          uint4 w4 = wr[q4];
          acc[c] += __popc((A[q4 * 4 + 0] ^ w4.x) & m) +
                    __popc((A[q4 * 4 + 1] ^ w4.y) & m) +
                    __popc((A[q4 * 4 + 2] ^ w4.z) & m) +
                    __popc((A[q4 * 4 + 3] ^ w4.w) & m);
        }
      }
    }
  }

  const int base = 32 * W * V;
  const u32 jbase = ((u32)(n * Cout + c0) << 10) | (u32)(y * 32 + xx);
  u32 packed = 0;
#pragma unroll
  for (int c = 0; c < 32; ++c) {
    float yv = (float)(base - 2 * acc[c]) + bias[c0 + c];
    bool neg = act_neg(yv, k0, k1, jbase + ((u32)c << 10));
    packed |= (neg ? 1u : 0u) << c;
  }
  out[(u32)(n * WOUT + z) * 1024u + (u32)(y * 32 + xx)] = packed;
}

// ---------------------------------------------------------------------------
// Repack conv6 PLANAR output into FC1 row layout (x-packed).
// ---------------------------------------------------------------------------
__global__ void k_repack(const u32* __restrict__ a6, u32* __restrict__ f0) {
  int idx = blockIdx.x * blockDim.x + threadIdx.x;
  if (idx >= 4096 * 256) return;
  int w = idx & 255, r = idx >> 8;
  int n = r >> 6, chi = r & 63;
  int clo = w >> 5, yy = w & 31;
  int c = chi * 8 + clo;
  const u32* base = a6 + (u32)(n * 16 + (c >> 5)) * 1024u + (u32)(yy * 32);
  u32 sh = (u32)(c & 31);
  u32 word = 0;
#pragma unroll
  for (int xp = 0; xp < 32; ++xp)
    word |= ((base[xp] >> sh) & 1u) << xp;
  f0[idx] = word;
}

// ---------------------------------------------------------------------------
// Binary FC with transposed weights (proven round 4). Block 256 = 4 waves;
// 32 rows (LDS) x 64 outputs; wave handles 8 rows; lane = o.
// ---------------------------------------------------------------------------
template <int KW>
__global__ __launch_bounds__(256, 4) void k_fct(
    const u32* __restrict__ in, const u32* __restrict__ pwT,
    const float* __restrict__ bias, int O, u32 k0, u32 k1,
    u32* __restrict__ out) {
  const int tid = threadIdx.x, lane = tid & 63;
  const int wv = __builtin_amdgcn_readfirstlane(tid >> 6);
  const int rbase = blockIdx.x * 32;
  const int obase = blockIdx.y * 64;
  __shared__ __align__(16) u32 rows[32 * KW];
  for (int i = tid; i < 32 * KW; i += 256)
    rows[i] = in[(size_t)(rbase + i / KW) * KW + (i % KW)];
  __syncthreads();

  const int o = obase + lane;
  const int r0 = wv * 8;
  u32 acc[8];
#pragma unroll
  for (int rr = 0; rr < 8; ++rr) acc[rr] = 0;
  for (int k4 = 0; k4 < KW / 4; ++k4) {
    uint4 w4 = ((const uint4*)pwT)[(size_t)k4 * O + o];
#pragma unroll
    for (int rr = 0; rr < 8; ++rr) {
      uint4 av = *(const uint4*)&rows[(r0 + rr) * KW + k4 * 4];
      acc[rr] += __popc(av.x ^ w4.x) + __popc(av.y ^ w4.y) +
                 __popc(av.z ^ w4.z) + __popc(av.w ^ w4.w);
    }
  }
  const int OW = O >> 5;
  const float bo = bias[o];
#pragma unroll
  for (int rr = 0; rr < 8; ++rr) {
    int r = rbase + r0 + rr;
    float yv = (float)(KW * 32 - 2 * (int)acc[rr]) + bo;
    bool neg = act_neg(yv, k0, k1, (u32)r * (u32)O + (u32)o);
    u64 b = __ballot(neg);
    if (lane == 0) {
      out[(size_t)r * OW + (obase >> 5)] = (u32)b;
      out[(size_t)r * OW + (obase >> 5) + 1] = (u32)(b >> 32);
    }
  }
}

// FC3: [4096][32 words] x [10][32 words] -> fp32 +-1 output [4096][10].
__global__ __launch_bounds__(64) void k_fc3(
    const u32* __restrict__ in, const u32* __restrict__ pw,
    const float* __restrict__ bias, u32 k0, u32 k1,
    float* __restrict__ outp) {
  const int lane = threadIdx.x;
  const int r = blockIdx.x;
  __shared__ u32 row[32];
  if (lane < 32) row[lane] = in[(size_t)r * 32 + lane];
  __syncthreads();
  if (lane < 10) {
    int acc = 0;
#pragma unroll
    for (int k = 0; k < 32; ++k) acc += __popc(row[k] ^ pw[lane * 32 + k]);
    float yv = (float)(1024 - 2 * acc) + bias[lane];
    bool neg = act_neg(yv, k0, k1, (u32)r * 10u + (u32)lane);
    outp[(size_t)r * 10 + lane] = neg ? -1.0f : 1.0f;
  }
}

// ---------------------------------------------------------------------------
extern "C" void kernel_launch(void* const* d_in, const int* in_sizes, int n_in,
                              void* d_out, int out_size, void* d_ws,
                              size_t ws_size, hipStream_t stream) {
  const float* x   = (const float*)d_in[0];
  const float* w1  = (const float*)d_in[1];
  const float* b1  = (const float*)d_in[2];
  const float* w2  = (const float*)d_in[3];
  const float* b2  = (const float*)d_in[4];
  const float* w3  = (const float*)d_in[5];
  const float* b3  = (const float*)d_in[6];
  const float* w4  = (const float*)d_in[7];
  const float* b4  = (const float*)d_in[8];
  const float* w5  = (const float*)d_in[9];
  const float* b5  = (const float*)d_in[10];
  const float* w6  = (const float*)d_in[11];
  const float* b6  = (const float*)d_in[12];
  const float* fw1 = (const float*)d_in[13];
  const float* fb1 = (const float*)d_in[14];
  const float* fw2 = (const float*)d_in[15];
  const float* fb2 = (const float*)d_in[16];
  const float* fw3 = (const float*)d_in[17];
  const float* fb3 = (const float*)d_in[18];

  u32 K[9][2];
  for (int i = 0; i < 9; ++i) tf2x32(0u, 42u, 0u, (u32)i, K[i][0], K[i][1]);

  char* ws = (char*)d_ws;
  size_t off = 0;
  auto alloc = [&](size_t bytes) -> char* {
    char* p = ws + off;
    off += (bytes + 255) & ~(size_t)255;
    return p;
  };
  u32* pw2  = (u32*)alloc(256u * 9 * 4 * 4);
  u32* pw3  = (u32*)alloc(256u * 9 * 8 * 4);
  u32* pw4  = (u32*)alloc(256u * 9 * 8 * 4);
  u32* pw5  = (u32*)alloc(512u * 9 * 8 * 4);
  u32* pw6  = (u32*)alloc(512u * 9 * 16 * 4);
  u32* pfw1 = (u32*)alloc(1024u * 256 * 4);
  u32* pfw2 = (u32*)alloc(1024u * 32 * 4);
  u32* pfw3 = (u32*)alloc(10u * 32 * 4);
  u32* a1   = (u32*)alloc(64u * 1024 * 4 * 4);
  u32* a2   = (u32*)alloc(64u * 1024 * 8 * 4);
  u32* a3   = (u32*)alloc(64u * 1024 * 8 * 4);
  u32* a4   = (u32*)alloc(64u * 1024 * 8 * 4);
  u32* a5   = (u32*)alloc(64u * 1024 * 16 * 4);
  u32* a6   = (u32*)alloc(64u * 1024 * 16 * 4);
  u32* f0   = (u32*)alloc(4096u * 256 * 4);
  u32* f1   = (u32*)alloc(4096u * 32 * 4);
  u32* f2   = (u32*)alloc(4096u * 32 * 4);
  (void)ws_size;  // ~23 MB of workspace

  int t;
  t = 256 * 9 * 4;
  k_pack_convw<<<(t + 255) / 256, 256, 0, stream>>>(w2, pw2, 256, 128);
  t = 256 * 9 * 8;
  k_pack_convw<<<(t + 255) / 256, 256, 0, stream>>>(w3, pw3, 256, 256);
  k_pack_convw<<<(t + 255) / 256, 256, 0, stream>>>(w4, pw4, 256, 256);
  t = 512 * 9 * 8;
  k_pack_convw<<<(t + 255) / 256, 256, 0, stream>>>(w5, pw5, 512, 256);
  t = 512 * 9 * 16;
  k_pack_convw<<<(t + 255) / 256, 256, 0, stream>>>(w6, pw6, 512, 512);
  t = 1024 * 256;
  k_pack_fcwT<<<(t + 255) / 256, 256, 0, stream>>>(fw1, pfw1, 1024, 8192);
  t = 1024 * 32;
  k_pack_fcwT<<<(t + 255) / 256, 256, 0, stream>>>(fw2, pfw2, 1024, 1024);
  t = 10 * 32;
  k_pack_fcw<<<(t + 255) / 256, 256, 0, stream>>>(fw3, pfw3, 10, 1024);

  k_conv1<<<16384, 256, 0, stream>>>(x, w1, b1, K[0][0], K[0][1], a1);
  k_bconv5<4><<<dim3(64, 4, 8), 256, 0, stream>>>(a1, pw2, b2, 256,
                                                  K[1][0], K[1][1], a2);
  k_bconv5<8><<<dim3(64, 4, 8), 256, 0, stream>>>(a2, pw3, b3, 256,
                                                  K[2][0], K[2][1], a3);
  k_bconv5<8><<<dim3(64, 4, 8), 256, 0, stream>>>(a3, pw4, b4, 256,
                                                  K[3][0], K[3][1], a4);
  k_bconv5<8><<<dim3(64, 4, 16), 256, 0, stream>>>(a4, pw5, b5, 512,
                                                   K[4][0], K[4][1], a5);
  k_bconv5<16><<<dim3(64, 4, 16), 256, 0, stream>>>(a5, pw6, b6, 512,
                                                    K[5][0], K[5][1], a6);
  k_repack<<<(4096 * 256 + 255) / 256, 256, 0, stream>>>(a6, f0);
  k_fct<256><<<dim3(128, 16), 256, 0, stream>>>(f0, pfw1, fb1, 1024,
                                                K[6][0], K[6][1], f1);
  k_fct<32><<<dim3(128, 16), 256, 0, stream>>>(f1, pfw2, fb2, 1024,
                                               K[7][0], K[7][1], f2);
  k_fc3<<<4096, 64, 0, stream>>>(f2, pfw3, fb3, K[8][0], K[8][1],
                                 (float*)d_out);
}

// Round 8
// 840.026 us; speedup vs baseline: 15.3803x; 1.5557x over previous
//
#include <hip/hip_runtime.h>
#include <stdint.h>

typedef unsigned int u32;
typedef unsigned long long u64;
typedef int v4i __attribute__((ext_vector_type(4)));
typedef int v16i __attribute__((ext_vector_type(16)));

// ---------------------------------------------------------------------------
// Threefry-2x32, 20 rounds — bit-exact replica of JAX's threefry2x32 primitive.
// ---------------------------------------------------------------------------
__host__ __device__ __forceinline__ void tf2x32(u32 k0, u32 k1, u32 x0, u32 x1,
                                                u32& o0, u32& o1) {
  u32 k2 = k0 ^ k1 ^ 0x1BD11BDAu;
  x0 += k0; x1 += k1;
#define TFR(r) { x0 += x1; x1 = (x1 << (r)) | (x1 >> (32 - (r))); x1 ^= x0; }
  TFR(13) TFR(15) TFR(26) TFR(6)   x0 += k1; x1 += k2 + 1u;
  TFR(17) TFR(29) TFR(16) TFR(24)  x0 += k2; x1 += k0 + 2u;
  TFR(13) TFR(15) TFR(26) TFR(6)   x0 += k0; x1 += k1 + 3u;
  TFR(17) TFR(29) TFR(16) TFR(24)  x0 += k1; x1 += k2 + 4u;
  TFR(13) TFR(15) TFR(26) TFR(6)   x0 += k2; x1 += k0 + 5u;
#undef TFR
  o0 = x0; o1 = x1;
}

// stoch_act: p = clip((y+1)*0.5, 0, 1); u from partitionable random bits of
// flat index j: bits = o0 ^ o1 of TF(key, (0, j)). Returns true if out = -1.
__device__ __forceinline__ bool act_neg(float y, u32 k0, u32 k1, u32 j) {
  u32 o0, o1;
  tf2x32(k0, k1, 0u, j, o0, o1);
  u32 bits = o0 ^ o1;
  float u = __uint_as_float(0x3f800000u | (bits >> 9)) - 1.0f;
  float t = (y + 1.0f) * 0.5f;
  float p = fminf(fmaxf(t, 0.0f), 1.0f);
  return !(u < p);
}

// ---------------------------------------------------------------------------
// Conv weight pack directly into i8 MFMA B-fragment order.
// Layout (u32 units): bf[((cot*W + kt)*9 + t)*256 + l*4 + i4], bytes b: 
//   co = cot*32 + (l&31), ci = kt*32 + (l>>5)*16 + i4*4 + b, tap t.
// i8 = +1 if w>=0 else -1 (0x01 / 0xFF).
// ---------------------------------------------------------------------------
__global__ void k_pack_wfrag(const float* __restrict__ w, u32* __restrict__ bf,
                             int Cout, int Cin) {
  const int W = Cin >> 5;
  const int total = (Cout >> 5) * W * 9 * 256;
  int idx = blockIdx.x * blockDim.x + threadIdx.x;
  if (idx >= total) return;
  int i4 = idx & 3;
  int l = (idx >> 2) & 63;
  int t = (idx >> 8) % 9;
  int kt = (idx / 2304) % W;
  int cot = idx / (2304 * W);
  int co = cot * 32 + (l & 31);
  int ci0 = kt * 32 + (l >> 5) * 16 + i4 * 4;
  int kh = t / 3, kw = t % 3;
  u32 v = 0;
#pragma unroll
  for (int b = 0; b < 4; ++b) {
    float wf = w[((size_t)(co * Cin + ci0 + b) * 3 + kh) * 3 + kw];
    v |= (wf < 0.0f ? 0xFFu : 0x01u) << (8 * b);
  }
  bf[idx] = v;
}

// FC weight pack, transposed for coalesced lane=o loads: pwT[k4][o][j].
__global__ void k_pack_fcwT(const float* __restrict__ w, u32* __restrict__ pwT,
                            int O, int K) {
  int KW = K >> 5;
  int idx = blockIdx.x * blockDim.x + threadIdx.x;
  if (idx >= O * KW) return;
  int kw = idx % KW, o = idx / KW;
  u32 word = 0;
  for (int b = 0; b < 32; ++b)
    word |= (w[(size_t)o * K + kw * 32 + b] < 0.0f ? 1u : 0u) << b;
  int k4 = kw >> 2, j = kw & 3;
  pwT[((size_t)k4 * O + o) * 4 + j] = word;
}

// FC weight pack, row-major (fc3).
__global__ void k_pack_fcw(const float* __restrict__ w, u32* __restrict__ pw,
                           int O, int K) {
  int KW = K >> 5;
  int idx = blockIdx.x * blockDim.x + threadIdx.x;
  if (idx >= O * KW) return;
  int kw = idx % KW, o = idx / KW;
  u32 word = 0;
  for (int b = 0; b < 32; ++b)
    word |= (w[o * K + kw * 32 + b] < 0.0f ? 1u : 0u) << b;
  pw[idx] = word;
}

// ---------------------------------------------------------------------------
// conv1: fp32 x [64][3][32][32], binarized w1, +b1, stoch_act key0.
// Output PLANAR packed: a1[(n*4 + w)*1024 + y*32 + x]. One wave per (n,y,x).
// ---------------------------------------------------------------------------
__global__ __launch_bounds__(256) void k_conv1(
    const float* __restrict__ x, const float* __restrict__ w1,
    const float* __restrict__ b1, u32 k0, u32 k1, u32* __restrict__ out) {
  int wave = (blockIdx.x * 256 + threadIdx.x) >> 6;
  int lane = threadIdx.x & 63;
  int n = wave >> 10;
  int rem = wave & 1023;
  int y = rem >> 5, xx = rem & 31;

  float xv[27];
#pragma unroll
  for (int ci = 0; ci < 3; ++ci)
#pragma unroll
    for (int dy = -1; dy <= 1; ++dy)
#pragma unroll
      for (int dx = -1; dx <= 1; ++dx) {
        int gy = y + dy, gx = xx + dx;
        float v = 0.0f;
        if ((unsigned)gy < 32u && (unsigned)gx < 32u)
          v = x[((n * 3 + ci) * 32 + gy) * 32 + gx];
        xv[(ci * 3 + (dy + 1)) * 3 + (dx + 1)] = v;
      }

  u64 bm[2];
#pragma unroll
  for (int h = 0; h < 2; ++h) {
    int co = lane + h * 64;
    float acc = 0.0f;
#pragma unroll
    for (int kh = 0; kh < 3; ++kh)
#pragma unroll
      for (int kw = 0; kw < 3; ++kw)
#pragma unroll
        for (int ci = 0; ci < 3; ++ci) {
          int k = (ci * 3 + kh) * 3 + kw;
          float wv = w1[co * 27 + k];
          acc += (wv < 0.0f) ? -xv[k] : xv[k];
        }
    float yv = acc + b1[co];
    u32 j = ((u32)(n * 128 + co) << 10) | (u32)(y << 5) | (u32)xx;
    bm[h] = __ballot(act_neg(yv, k0, k1, j));
  }
  if (lane < 4) {
    u32 wsel = (lane & 1) ? (u32)(bm[lane >> 1] >> 32) : (u32)bm[lane >> 1];
    out[(u32)(n * 4 + lane) * 1024u + (u32)(y * 32 + xx)] = wsel;
  }
}

// ---------------------------------------------------------------------------
// Binary conv via i8 MFMA (layers 2..6). Exact: activations/weights are ±1,
// zero-padding is true i8 zero -> contributes 0 to the i32 dot (no masks).
// Block = 256 thr = 4 waves; M = 128 pixels (4 y-rows x 32 x); wave wv owns
// cout tile cot = z*4+wv (32 couts). K-loop over ci-slices (kt) x 9 taps.
// Per kt: expand packed plane kt into i8 LDS slice [6 rows][34 x][32 ci]
// (rows y0-1..y0+4, x -1..32, zeros OOB). A-frag: ds_read_b128 at
// (srow*34 + (l&31)+dx+1)*32 + (l>>5)*16. B-frag: global fragment buffer.
// MFMA layouts: A row=l&31,k=16*(l>>5)+e; B col=l&31 same k; D col=l&31,
// row=(reg&3)+8*(reg>>2)+4*(l>>5).
// ---------------------------------------------------------------------------
template <int W>
__global__ __launch_bounds__(256) void k_bconv6(
    const u32* __restrict__ in, const u32* __restrict__ bfrag,
    const float* __restrict__ bias, int Cout, u32 k0, u32 k1,
    u32* __restrict__ out) {
  const int tid = threadIdx.x;
  const int lane = tid & 63;
  const int wv = tid >> 6;
  const int n = blockIdx.x;
  const int y0 = blockIdx.y * 4;
  const int cot = blockIdx.z * 4 + wv;
  const int WOUT = Cout >> 5;

  __shared__ __align__(16) char sl[6 * 34 * 32];

  v16i acc[4];
#pragma unroll
  for (int r = 0; r < 4; ++r)
#pragma unroll
    for (int e = 0; e < 16; ++e) acc[r][e] = 0;

#pragma unroll 1
  for (int kt = 0; kt < W; ++kt) {
    // Expand ci-slice kt into LDS (i8 +-1, true 0 for OOB).
    for (int i = tid; i < 6 * 34 * 8; i += 256) {
      int ci4 = i & 7;
      int xc = (i >> 3) % 34;
      int r = i / 272;
      int gy = y0 - 1 + r, gx = xc - 1;
      u32 val = 0;
      if ((unsigned)gy < 32u && (unsigned)gx < 32u) {
        u32 word = in[(u32)(n * W + kt) * 1024u + (u32)(gy * 32 + gx)];
        u32 nib = (word >> (ci4 * 4)) & 0xFu;
        u32 spread = (nib * 0x00204081u) & 0x01010101u;
        val = (spread * 0xFEu) ^ 0x01010101u;
      }
      ((u32*)sl)[(r * 34 + xc) * 8 + ci4] = val;
    }
    __syncthreads();

    const u32* bptr = bfrag + ((size_t)(cot * W + kt) * 9) * 256 + lane * 4;
#pragma unroll
    for (int t = 0; t < 9; ++t) {
      v4i B = *(const v4i*)(bptr + t * 256);
      const int dy = t / 3 - 1, dx = t % 3 - 1;
#pragma unroll
      for (int r = 0; r < 4; ++r) {
        const int srow = r + dy + 1;  // 0..5
        v4i A = *(const v4i*)&sl[((srow * 34) + (lane & 31) + dx + 1) * 32 +
                                 (lane >> 5) * 16];
        acc[r] = __builtin_amdgcn_mfma_i32_32x32x32_i8(A, B, acc[r], 0, 0, 0);
      }
    }
    __syncthreads();
  }

  // Epilogue: bias + stoch_act + ballot-pack into planar channel words.
  const int co = cot * 32 + (lane & 31);
  const float bo = bias[co];
  const u32 jb = (u32)(n * Cout + co) * 1024u;
#pragma unroll
  for (int r = 0; r < 4; ++r) {
    const int y = y0 + r;
#pragma unroll
    for (int reg = 0; reg < 16; ++reg) {
      const int mlo = (reg & 3) + 8 * (reg >> 2);
      const int m = mlo + 4 * (lane >> 5);
      float yv = (float)acc[r][reg] + bo;
      bool neg = act_neg(yv, k0, k1, jb + (u32)(y * 32 + m));
      u64 b = __ballot(neg);
      if (lane == 0)
        out[(u32)(n * WOUT + cot) * 1024u + (u32)(y * 32 + mlo)] = (u32)b;
      else if (lane == 32)
        out[(u32)(n * WOUT + cot) * 1024u + (u32)(y * 32 + mlo + 4)] =
            (u32)(b >> 32);
    }
  }
}

// ---------------------------------------------------------------------------
// Repack conv6 PLANAR output into FC1 row layout (x-packed).
// ---------------------------------------------------------------------------
__global__ void k_repack(const u32* __restrict__ a6, u32* __restrict__ f0) {
  int idx = blockIdx.x * blockDim.x + threadIdx.x;
  if (idx >= 4096 * 256) return;
  int w = idx & 255, r = idx >> 8;
  int n = r >> 6, chi = r & 63;
  int clo = w >> 5, yy = w & 31;
  int c = chi * 8 + clo;
  const u32* base = a6 + (u32)(n * 16 + (c >> 5)) * 1024u + (u32)(yy * 32);
  u32 sh = (u32)(c & 31);
  u32 word = 0;
#pragma unroll
  for (int xp = 0; xp < 32; ++xp)
    word |= ((base[xp] >> sh) & 1u) << xp;
  f0[idx] = word;
}

// ---------------------------------------------------------------------------
// Binary FC with transposed weights (proven round 4). Block 256 = 4 waves;
// 32 rows (LDS) x 64 outputs; wave handles 8 rows; lane = o.
// ---------------------------------------------------------------------------
template <int KW>
__global__ __launch_bounds__(256, 4) void k_fct(
    const u32* __restrict__ in, const u32* __restrict__ pwT,
    const float* __restrict__ bias, int O, u32 k0, u32 k1,
    u32* __restrict__ out) {
  const int tid = threadIdx.x, lane = tid & 63;
  const int wv = __builtin_amdgcn_readfirstlane(tid >> 6);
  const int rbase = blockIdx.x * 32;
  const int obase = blockIdx.y * 64;
  __shared__ __align__(16) u32 rows[32 * KW];
  for (int i = tid; i < 32 * KW; i += 256)
    rows[i] = in[(size_t)(rbase + i / KW) * KW + (i % KW)];
  __syncthreads();

  const int o = obase + lane;
  const int r0 = wv * 8;
  u32 acc[8];
#pragma unroll
  for (int rr = 0; rr < 8; ++rr) acc[rr] = 0;
  for (int k4 = 0; k4 < KW / 4; ++k4) {
    uint4 w4 = ((const uint4*)pwT)[(size_t)k4 * O + o];
#pragma unroll
    for (int rr = 0; rr < 8; ++rr) {
      uint4 av = *(const uint4*)&rows[(r0 + rr) * KW + k4 * 4];
      acc[rr] += __popc(av.x ^ w4.x) + __popc(av.y ^ w4.y) +
                 __popc(av.z ^ w4.z) + __popc(av.w ^ w4.w);
    }
  }
  const int OW = O >> 5;
  const float bo = bias[o];
#pragma unroll
  for (int rr = 0; rr < 8; ++rr) {
    int r = rbase + r0 + rr;
    float yv = (float)(KW * 32 - 2 * (int)acc[rr]) + bo;
    bool neg = act_neg(yv, k0, k1, (u32)r * (u32)O + (u32)o);
    u64 b = __ballot(neg);
    if (lane == 0) {
      out[(size_t)r * OW + (obase >> 5)] = (u32)b;
      out[(size_t)r * OW + (obase >> 5) + 1] = (u32)(b >> 32);
    }
  }
}

// FC3: [4096][32 words] x [10][32 words] -> fp32 +-1 output [4096][10].
__global__ __launch_bounds__(64) void k_fc3(
    const u32* __restrict__ in, const u32* __restrict__ pw,
    const float* __restrict__ bias, u32 k0, u32 k1,
    float* __restrict__ outp) {
  const int lane = threadIdx.x;
  const int r = blockIdx.x;
  __shared__ u32 row[32];
  if (lane < 32) row[lane] = in[(size_t)r * 32 + lane];
  __syncthreads();
  if (lane < 10) {
    int acc = 0;
#pragma unroll
    for (int k = 0; k < 32; ++k) acc += __popc(row[k] ^ pw[lane * 32 + k]);
    float yv = (float)(1024 - 2 * acc) + bias[lane];
    bool neg = act_neg(yv, k0, k1, (u32)r * 10u + (u32)lane);
    outp[(size_t)r * 10 + lane] = neg ? -1.0f : 1.0f;
  }
}

// ---------------------------------------------------------------------------
extern "C" void kernel_launch(void* const* d_in, const int* in_sizes, int n_in,
                              void* d_out, int out_size, void* d_ws,
                              size_t ws_size, hipStream_t stream) {
  const float* x   = (const float*)d_in[0];
  const float* w1  = (const float*)d_in[1];
  const float* b1  = (const float*)d_in[2];
  const float* w2  = (const float*)d_in[3];
  const float* b2  = (const float*)d_in[4];
  const float* w3  = (const float*)d_in[5];
  const float* b3  = (const float*)d_in[6];
  const float* w4  = (const float*)d_in[7];
  const float* b4  = (const float*)d_in[8];
  const float* w5  = (const float*)d_in[9];
  const float* b5  = (const float*)d_in[10];
  const float* w6  = (const float*)d_in[11];
  const float* b6  = (const float*)d_in[12];
  const float* fw1 = (const float*)d_in[13];
  const float* fb1 = (const float*)d_in[14];
  const float* fw2 = (const float*)d_in[15];
  const float* fb2 = (const float*)d_in[16];
  const float* fw3 = (const float*)d_in[17];
  const float* fb3 = (const float*)d_in[18];

  u32 K[9][2];
  for (int i = 0; i < 9; ++i) tf2x32(0u, 42u, 0u, (u32)i, K[i][0], K[i][1]);

  char* ws = (char*)d_ws;
  size_t off = 0;
  auto alloc = [&](size_t bytes) -> char* {
    char* p = ws + off;
    off += (bytes + 255) & ~(size_t)255;
    return p;
  };
  // i8 MFMA weight fragment buffers: Cout*9*Cin bytes each.
  u32* bf2  = (u32*)alloc(256u * 9 * 128);
  u32* bf3  = (u32*)alloc(256u * 9 * 256);
  u32* bf4  = (u32*)alloc(256u * 9 * 256);
  u32* bf5  = (u32*)alloc(512u * 9 * 256);
  u32* bf6  = (u32*)alloc(512u * 9 * 512);
  u32* pfw1 = (u32*)alloc(1024u * 256 * 4);
  u32* pfw2 = (u32*)alloc(1024u * 32 * 4);
  u32* pfw3 = (u32*)alloc(10u * 32 * 4);
  u32* a1   = (u32*)alloc(64u * 1024 * 4 * 4);
  u32* a2   = (u32*)alloc(64u * 1024 * 8 * 4);
  u32* a3   = (u32*)alloc(64u * 1024 * 8 * 4);
  u32* a4   = (u32*)alloc(64u * 1024 * 8 * 4);
  u32* a5   = (u32*)alloc(64u * 1024 * 16 * 4);
  u32* a6   = (u32*)alloc(64u * 1024 * 16 * 4);
  u32* f0   = (u32*)alloc(4096u * 256 * 4);
  u32* f1   = (u32*)alloc(4096u * 32 * 4);
  u32* f2   = (u32*)alloc(4096u * 32 * 4);
  (void)ws_size;  // ~27 MB of workspace

  int t;
  t = (256 / 32) * 4 * 9 * 256;
  k_pack_wfrag<<<(t + 255) / 256, 256, 0, stream>>>(w2, bf2, 256, 128);
  t = (256 / 32) * 8 * 9 * 256;
  k_pack_wfrag<<<(t + 255) / 256, 256, 0, stream>>>(w3, bf3, 256, 256);
  k_pack_wfrag<<<(t + 255) / 256, 256, 0, stream>>>(w4, bf4, 256, 256);
  t = (512 / 32) * 8 * 9 * 256;
  k_pack_wfrag<<<(t + 255) / 256, 256, 0, stream>>>(w5, bf5, 512, 256);
  t = (512 / 32) * 16 * 9 * 256;
  k_pack_wfrag<<<(t + 255) / 256, 256, 0, stream>>>(w6, bf6, 512, 512);
  t = 1024 * 256;
  k_pack_fcwT<<<(t + 255) / 256, 256, 0, stream>>>(fw1, pfw1, 1024, 8192);
  t = 1024 * 32;
  k_pack_fcwT<<<(t + 255) / 256, 256, 0, stream>>>(fw2, pfw2, 1024, 1024);
  t = 10 * 32;
  k_pack_fcw<<<(t + 255) / 256, 256, 0, stream>>>(fw3, pfw3, 10, 1024);

  k_conv1<<<16384, 256, 0, stream>>>(x, w1, b1, K[0][0], K[0][1], a1);
  k_bconv6<4><<<dim3(64, 8, 2), 256, 0, stream>>>(a1, bf2, b2, 256,
                                                  K[1][0], K[1][1], a2);
  k_bconv6<8><<<dim3(64, 8, 2), 256, 0, stream>>>(a2, bf3, b3, 256,
                                                  K[2][0], K[2][1], a3);
  k_bconv6<8><<<dim3(64, 8, 2), 256, 0, stream>>>(a3, bf4, b4, 256,
                                                  K[3][0], K[3][1], a4);
  k_bconv6<8><<<dim3(64, 8, 4), 256, 0, stream>>>(a4, bf5, b5, 512,
                                                  K[4][0], K[4][1], a5);
  k_bconv6<16><<<dim3(64, 8, 4), 256, 0, stream>>>(a5, bf6, b6, 512,
                                                   K[5][0], K[5][1], a6);
  k_repack<<<(4096 * 256 + 255) / 256, 256, 0, stream>>>(a6, f0);
  k_fct<256><<<dim3(128, 16), 256, 0, stream>>>(f0, pfw1, fb1, 1024,
                                                K[6][0], K[6][1], f1);
  k_fct<32><<<dim3(128, 16), 256, 0, stream>>>(f1, pfw2, fb2, 1024,
                                               K[7][0], K[7][1], f2);
  k_fc3<<<4096, 64, 0, stream>>>(f2, pfw3, fb3, K[8][0], K[8][1],
                                 (float*)d_out);
}

// Round 9
// 822.472 us; speedup vs baseline: 15.7085x; 1.0213x over previous
//
#include <hip/hip_runtime.h>
#include <stdint.h>

typedef unsigned int u32;
typedef unsigned long long u64;
typedef int v4i __attribute__((ext_vector_type(4)));
typedef int v16i __attribute__((ext_vector_type(16)));

// ---------------------------------------------------------------------------
// Threefry-2x32, 20 rounds — bit-exact replica of JAX's threefry2x32 primitive.
// ---------------------------------------------------------------------------
__host__ __device__ __forceinline__ void tf2x32(u32 k0, u32 k1, u32 x0, u32 x1,
                                                u32& o0, u32& o1) {
  u32 k2 = k0 ^ k1 ^ 0x1BD11BDAu;
  x0 += k0; x1 += k1;
#define TFR(r) { x0 += x1; x1 = (x1 << (r)) | (x1 >> (32 - (r))); x1 ^= x0; }
  TFR(13) TFR(15) TFR(26) TFR(6)   x0 += k1; x1 += k2 + 1u;
  TFR(17) TFR(29) TFR(16) TFR(24)  x0 += k2; x1 += k0 + 2u;
  TFR(13) TFR(15) TFR(26) TFR(6)   x0 += k0; x1 += k1 + 3u;
  TFR(17) TFR(29) TFR(16) TFR(24)  x0 += k1; x1 += k2 + 4u;
  TFR(13) TFR(15) TFR(26) TFR(6)   x0 += k2; x1 += k0 + 5u;
#undef TFR
  o0 = x0; o1 = x1;
}

// stoch_act: p = clip((y+1)*0.5, 0, 1); u from partitionable random bits of
// flat index j: bits = o0 ^ o1 of TF(key, (0, j)). Returns true if out = -1.
__device__ __forceinline__ bool act_neg(float y, u32 k0, u32 k1, u32 j) {
  u32 o0, o1;
  tf2x32(k0, k1, 0u, j, o0, o1);
  u32 bits = o0 ^ o1;
  float u = __uint_as_float(0x3f800000u | (bits >> 9)) - 1.0f;
  float t = (y + 1.0f) * 0.5f;
  float p = fminf(fmaxf(t, 0.0f), 1.0f);
  return !(u < p);
}

// ---------------------------------------------------------------------------
// Conv weight pack directly into i8 MFMA B-fragment order.
// bf[((cot*W + kt)*9 + t)*256 + l*4 + i4], bytes b:
//   co = cot*32 + (l&31), ci = kt*32 + (l>>5)*16 + i4*4 + b, tap t.
// i8 = +1 if w>=0 else -1 (0x01 / 0xFF).
// ---------------------------------------------------------------------------
__global__ void k_pack_wfrag(const float* __restrict__ w, u32* __restrict__ bf,
                             int Cout, int Cin) {
  const int W = Cin >> 5;
  const int total = (Cout >> 5) * W * 9 * 256;
  int idx = blockIdx.x * blockDim.x + threadIdx.x;
  if (idx >= total) return;
  int i4 = idx & 3;
  int l = (idx >> 2) & 63;
  int t = (idx >> 8) % 9;
  int kt = (idx / 2304) % W;
  int cot = idx / (2304 * W);
  int co = cot * 32 + (l & 31);
  int ci0 = kt * 32 + (l >> 5) * 16 + i4 * 4;
  int kh = t / 3, kw = t % 3;
  u32 v = 0;
#pragma unroll
  for (int b = 0; b < 4; ++b) {
    float wf = w[((size_t)(co * Cin + ci0 + b) * 3 + kh) * 3 + kw];
    v |= (wf < 0.0f ? 0xFFu : 0x01u) << (8 * b);
  }
  bf[idx] = v;
}

// FC weight pack, transposed for coalesced lane=o loads: pwT[k4][o][j].
__global__ void k_pack_fcwT(const float* __restrict__ w, u32* __restrict__ pwT,
                            int O, int K) {
  int KW = K >> 5;
  int idx = blockIdx.x * blockDim.x + threadIdx.x;
  if (idx >= O * KW) return;
  int kw = idx % KW, o = idx / KW;
  u32 word = 0;
  for (int b = 0; b < 32; ++b)
    word |= (w[(size_t)o * K + kw * 32 + b] < 0.0f ? 1u : 0u) << b;
  int k4 = kw >> 2, j = kw & 3;
  pwT[((size_t)k4 * O + o) * 4 + j] = word;
}

// FC weight pack, row-major (fc3).
__global__ void k_pack_fcw(const float* __restrict__ w, u32* __restrict__ pw,
                           int O, int K) {
  int KW = K >> 5;
  int idx = blockIdx.x * blockDim.x + threadIdx.x;
  if (idx >= O * KW) return;
  int kw = idx % KW, o = idx / KW;
  u32 word = 0;
  for (int b = 0; b < 32; ++b)
    word |= (w[o * K + kw * 32 + b] < 0.0f ? 1u : 0u) << b;
  pw[idx] = word;
}

// ---------------------------------------------------------------------------
// conv1: fp32 x [64][3][32][32], binarized w1, +b1, stoch_act key0.
// Output PLANAR packed: a1[(n*4 + w)*1024 + y*32 + x]. One wave per (n,y,x).
// ---------------------------------------------------------------------------
__global__ __launch_bounds__(256) void k_conv1(
    const float* __restrict__ x, const float* __restrict__ w1,
    const float* __restrict__ b1, u32 k0, u32 k1, u32* __restrict__ out) {
  int wave = (blockIdx.x * 256 + threadIdx.x) >> 6;
  int lane = threadIdx.x & 63;
  int n = wave >> 10;
  int rem = wave & 1023;
  int y = rem >> 5, xx = rem & 31;

  float xv[27];
#pragma unroll
  for (int ci = 0; ci < 3; ++ci)
#pragma unroll
    for (int dy = -1; dy <= 1; ++dy)
#pragma unroll
      for (int dx = -1; dx <= 1; ++dx) {
        int gy = y + dy, gx = xx + dx;
        float v = 0.0f;
        if ((unsigned)gy < 32u && (unsigned)gx < 32u)
          v = x[((n * 3 + ci) * 32 + gy) * 32 + gx];
        xv[(ci * 3 + (dy + 1)) * 3 + (dx + 1)] = v;
      }

  u64 bm[2];
#pragma unroll
  for (int h = 0; h < 2; ++h) {
    int co = lane + h * 64;
    float acc = 0.0f;
#pragma unroll
    for (int kh = 0; kh < 3; ++kh)
#pragma unroll
      for (int kw = 0; kw < 3; ++kw)
#pragma unroll
        for (int ci = 0; ci < 3; ++ci) {
          int k = (ci * 3 + kh) * 3 + kw;
          float wv = w1[co * 27 + k];
          acc += (wv < 0.0f) ? -xv[k] : xv[k];
        }
    float yv = acc + b1[co];
    u32 j = ((u32)(n * 128 + co) << 10) | (u32)(y << 5) | (u32)xx;
    bm[h] = __ballot(act_neg(yv, k0, k1, j));
  }
  if (lane < 4) {
    u32 wsel = (lane & 1) ? (u32)(bm[lane >> 1] >> 32) : (u32)bm[lane >> 1];
    out[(u32)(n * 4 + lane) * 1024u + (u32)(y * 32 + xx)] = wsel;
  }
}

// ---------------------------------------------------------------------------
// Binary conv via i8 MFMA (layers 2..6), v7 — math identical to the proven
// r8 kernel; only the LDS layout and read schedule change:
//  - LDS slice transposed: sl[ci-dword 0..7][6 rows][36 x] (u32). Expand
//    writes are 2-way max; A reads are ds_read_b32 with lanes 0..31 on
//    consecutive banks (conflict-free; lane+32 is +864 dwords = bank-equal
//    -> 2-way, free).
//  - The 18 distinct A-fragments (6 srow x 3 dx) are loaded ONCE per kt into
//    registers af[6][3][4] (static indices), then 36 MFMAs consume them.
// ---------------------------------------------------------------------------
template <int W>
__global__ __launch_bounds__(256) void k_bconv7(
    const u32* __restrict__ in, const u32* __restrict__ bfrag,
    const float* __restrict__ bias, int Cout, u32 k0, u32 k1,
    u32* __restrict__ out) {
  const int tid = threadIdx.x;
  const int lane = tid & 63;
  const int wv = tid >> 6;
  const int n = blockIdx.x;
  const int y0 = blockIdx.y * 4;
  const int cot = blockIdx.z * 4 + wv;
  const int WOUT = Cout >> 5;

  __shared__ u32 sl[8 * 6 * 36];

  v16i acc[4];
#pragma unroll
  for (int r = 0; r < 4; ++r)
#pragma unroll
    for (int e = 0; e < 16; ++e) acc[r][e] = 0;

#pragma unroll 1
  for (int kt = 0; kt < W; ++kt) {
    // Expand ci-slice kt into LDS (i8 +-1, true 0 for OOB), transposed.
    for (int i = tid; i < 8 * 34 * 6; i += 256) {
      int ci4 = i & 7;
      int xc = (i >> 3) % 34;
      int r = i / 272;
      int gy = y0 - 1 + r, gx = xc - 1;
      u32 val = 0;
      if ((unsigned)gy < 32u && (unsigned)gx < 32u) {
        u32 word = in[(u32)(n * W + kt) * 1024u + (u32)(gy * 32 + gx)];
        u32 nib = (word >> (ci4 * 4)) & 0xFu;
        u32 spread = (nib * 0x00204081u) & 0x01010101u;
        val = (spread * 0xFEu) ^ 0x01010101u;
      }
      sl[(ci4 * 6 + r) * 36 + xc] = val;
    }
    __syncthreads();

    // Load the 18 distinct A-fragments into registers (conflict-free b32).
    u32 af[6][3][4];
    const int xb = lane & 31;
    const int cd0 = (lane >> 5) * 4;
#pragma unroll
    for (int sr = 0; sr < 6; ++sr)
#pragma unroll
      for (int dxx = 0; dxx < 3; ++dxx)
#pragma unroll
        for (int q = 0; q < 4; ++q)
          af[sr][dxx][q] = sl[((cd0 + q) * 6 + sr) * 36 + xb + dxx];

    const u32* bptr = bfrag + ((size_t)(cot * W + kt) * 9) * 256 + lane * 4;
#pragma unroll
    for (int t = 0; t < 9; ++t) {
      v4i B = *(const v4i*)(bptr + t * 256);
      const int dy = t / 3 - 1, dxx = t % 3;
#pragma unroll
      for (int r = 0; r < 4; ++r) {
        v4i A;
        A[0] = (int)af[r + dy + 1][dxx][0];
        A[1] = (int)af[r + dy + 1][dxx][1];
        A[2] = (int)af[r + dy + 1][dxx][2];
        A[3] = (int)af[r + dy + 1][dxx][3];
        acc[r] = __builtin_amdgcn_mfma_i32_32x32x32_i8(A, B, acc[r], 0, 0, 0);
      }
    }
    __syncthreads();
  }

  // Epilogue: bias + stoch_act + ballot-pack into planar channel words.
  const int co = cot * 32 + (lane & 31);
  const float bo = bias[co];
  const u32 jb = (u32)(n * Cout + co) * 1024u;
#pragma unroll
  for (int r = 0; r < 4; ++r) {
    const int y = y0 + r;
#pragma unroll
    for (int reg = 0; reg < 16; ++reg) {
      const int mlo = (reg & 3) + 8 * (reg >> 2);
      const int m = mlo + 4 * (lane >> 5);
      float yv = (float)acc[r][reg] + bo;
      bool neg = act_neg(yv, k0, k1, jb + (u32)(y * 32 + m));
      u64 b = __ballot(neg);
      if (lane == 0)
        out[(u32)(n * WOUT + cot) * 1024u + (u32)(y * 32 + mlo)] = (u32)b;
      else if (lane == 32)
        out[(u32)(n * WOUT + cot) * 1024u + (u32)(y * 32 + mlo + 4)] =
            (u32)(b >> 32);
    }
  }
}

// ---------------------------------------------------------------------------
// Repack conv6 PLANAR output into FC1 row layout (x-packed).
// ---------------------------------------------------------------------------
__global__ void k_repack(const u32* __restrict__ a6, u32* __restrict__ f0) {
  int idx = blockIdx.x * blockDim.x + threadIdx.x;
  if (idx >= 4096 * 256) return;
  int w = idx & 255, r = idx >> 8;
  int n = r >> 6, chi = r & 63;
  int clo = w >> 5, yy = w & 31;
  int c = chi * 8 + clo;
  const u32* base = a6 + (u32)(n * 16 + (c >> 5)) * 1024u + (u32)(yy * 32);
  u32 sh = (u32)(c & 31);
  u32 word = 0;
#pragma unroll
  for (int xp = 0; xp < 32; ++xp)
    word |= ((base[xp] >> sh) & 1u) << xp;
  f0[idx] = word;
}

// ---------------------------------------------------------------------------
// Binary FC with transposed weights (proven round 4). Block 256 = 4 waves;
// 32 rows (LDS) x 64 outputs; wave handles 8 rows; lane = o.
// ---------------------------------------------------------------------------
template <int KW>
__global__ __launch_bounds__(256, 4) void k_fct(
    const u32* __restrict__ in, const u32* __restrict__ pwT,
    const float* __restrict__ bias, int O, u32 k0, u32 k1,
    u32* __restrict__ out) {
  const int tid = threadIdx.x, lane = tid & 63;
  const int wv = __builtin_amdgcn_readfirstlane(tid >> 6);
  const int rbase = blockIdx.x * 32;
  const int obase = blockIdx.y * 64;
  __shared__ __align__(16) u32 rows[32 * KW];
  for (int i = tid; i < 32 * KW; i += 256)
    rows[i] = in[(size_t)(rbase + i / KW) * KW + (i % KW)];
  __syncthreads();

  const int o = obase + lane;
  const int r0 = wv * 8;
  u32 acc[8];
#pragma unroll
  for (int rr = 0; rr < 8; ++rr) acc[rr] = 0;
  for (int k4 = 0; k4 < KW / 4; ++k4) {
    uint4 w4 = ((const uint4*)pwT)[(size_t)k4 * O + o];
#pragma unroll
    for (int rr = 0; rr < 8; ++rr) {
      uint4 av = *(const uint4*)&rows[(r0 + rr) * KW + k4 * 4];
      acc[rr] += __popc(av.x ^ w4.x) + __popc(av.y ^ w4.y) +
                 __popc(av.z ^ w4.z) + __popc(av.w ^ w4.w);
    }
  }
  const int OW = O >> 5;
  const float bo = bias[o];
#pragma unroll
  for (int rr = 0; rr < 8; ++rr) {
    int r = rbase + r0 + rr;
    float yv = (float)(KW * 32 - 2 * (int)acc[rr]) + bo;
    bool neg = act_neg(yv, k0, k1, (u32)r * (u32)O + (u32)o);
    u64 b = __ballot(neg);
    if (lane == 0) {
      out[(size_t)r * OW + (obase >> 5)] = (u32)b;
      out[(size_t)r * OW + (obase >> 5) + 1] = (u32)(b >> 32);
    }
  }
}

// FC3: [4096][32 words] x [10][32 words] -> fp32 +-1 output [4096][10].
__global__ __launch_bounds__(64) void k_fc3(
    const u32* __restrict__ in, const u32* __restrict__ pw,
    const float* __restrict__ bias, u32 k0, u32 k1,
    float* __restrict__ outp) {
  const int lane = threadIdx.x;
  const int r = blockIdx.x;
  __shared__ u32 row[32];
  if (lane < 32) row[lane] = in[(size_t)r * 32 + lane];
  __syncthreads();
  if (lane < 10) {
    int acc = 0;
#pragma unroll
    for (int k = 0; k < 32; ++k) acc += __popc(row[k] ^ pw[lane * 32 + k]);
    float yv = (float)(1024 - 2 * acc) + bias[lane];
    bool neg = act_neg(yv, k0, k1, (u32)r * 10u + (u32)lane);
    outp[(size_t)r * 10 + lane] = neg ? -1.0f : 1.0f;
  }
}

// ---------------------------------------------------------------------------
extern "C" void kernel_launch(void* const* d_in, const int* in_sizes, int n_in,
                              void* d_out, int out_size, void* d_ws,
                              size_t ws_size, hipStream_t stream) {
  const float* x   = (const float*)d_in[0];
  const float* w1  = (const float*)d_in[1];
  const float* b1  = (const float*)d_in[2];
  const float* w2  = (const float*)d_in[3];
  const float* b2  = (const float*)d_in[4];
  const float* w3  = (const float*)d_in[5];
  const float* b3  = (const float*)d_in[6];
  const float* w4  = (const float*)d_in[7];
  const float* b4  = (const float*)d_in[8];
  const float* w5  = (const float*)d_in[9];
  const float* b5  = (const float*)d_in[10];
  const float* w6  = (const float*)d_in[11];
  const float* b6  = (const float*)d_in[12];
  const float* fw1 = (const float*)d_in[13];
  const float* fb1 = (const float*)d_in[14];
  const float* fw2 = (const float*)d_in[15];
  const float* fb2 = (const float*)d_in[16];
  const float* fw3 = (const float*)d_in[17];
  const float* fb3 = (const float*)d_in[18];

  u32 K[9][2];
  for (int i = 0; i < 9; ++i) tf2x32(0u, 42u, 0u, (u32)i, K[i][0], K[i][1]);

  char* ws = (char*)d_ws;
  size_t off = 0;
  auto alloc = [&](size_t bytes) -> char* {
    char* p = ws + off;
    off += (bytes + 255) & ~(size_t)255;
    return p;
  };
  // i8 MFMA weight fragment buffers: Cout*9*Cin bytes each.
  u32* bf2  = (u32*)alloc(256u * 9 * 128);
  u32* bf3  = (u32*)alloc(256u * 9 * 256);
  u32* bf4  = (u32*)alloc(256u * 9 * 256);
  u32* bf5  = (u32*)alloc(512u * 9 * 256);
  u32* bf6  = (u32*)alloc(512u * 9 * 512);
  u32* pfw1 = (u32*)alloc(1024u * 256 * 4);
  u32* pfw2 = (u32*)alloc(1024u * 32 * 4);
  u32* pfw3 = (u32*)alloc(10u * 32 * 4);
  u32* a1   = (u32*)alloc(64u * 1024 * 4 * 4);
  u32* a2   = (u32*)alloc(64u * 1024 * 8 * 4);
  u32* a3   = (u32*)alloc(64u * 1024 * 8 * 4);
  u32* a4   = (u32*)alloc(64u * 1024 * 8 * 4);
  u32* a5   = (u32*)alloc(64u * 1024 * 16 * 4);
  u32* a6   = (u32*)alloc(64u * 1024 * 16 * 4);
  u32* f0   = (u32*)alloc(4096u * 256 * 4);
  u32* f1   = (u32*)alloc(4096u * 32 * 4);
  u32* f2   = (u32*)alloc(4096u * 32 * 4);
  (void)ws_size;  // ~27 MB of workspace

  int t;
  t = (256 / 32) * 4 * 9 * 256;
  k_pack_wfrag<<<(t + 255) / 256, 256, 0, stream>>>(w2, bf2, 256, 128);
  t = (256 / 32) * 8 * 9 * 256;
  k_pack_wfrag<<<(t + 255) / 256, 256, 0, stream>>>(w3, bf3, 256, 256);
  k_pack_wfrag<<<(t + 255) / 256, 256, 0, stream>>>(w4, bf4, 256, 256);
  t = (512 / 32) * 8 * 9 * 256;
  k_pack_wfrag<<<(t + 255) / 256, 256, 0, stream>>>(w5, bf5, 512, 256);
  t = (512 / 32) * 16 * 9 * 256;
  k_pack_wfrag<<<(t + 255) / 256, 256, 0, stream>>>(w6, bf6, 512, 512);
  t = 1024 * 256;
  k_pack_fcwT<<<(t + 255) / 256, 256, 0, stream>>>(fw1, pfw1, 1024, 8192);
  t = 1024 * 32;
  k_pack_fcwT<<<(t + 255) / 256, 256, 0, stream>>>(fw2, pfw2, 1024, 1024);
  t = 10 * 32;
  k_pack_fcw<<<(t + 255) / 256, 256, 0, stream>>>(fw3, pfw3, 10, 1024);

  k_conv1<<<16384, 256, 0, stream>>>(x, w1, b1, K[0][0], K[0][1], a1);
  k_bconv7<4><<<dim3(64, 8, 2), 256, 0, stream>>>(a1, bf2, b2, 256,
                                                  K[1][0], K[1][1], a2);
  k_bconv7<8><<<dim3(64, 8, 2), 256, 0, stream>>>(a2, bf3, b3, 256,
                                                  K[2][0], K[2][1], a3);
  k_bconv7<8><<<dim3(64, 8, 2), 256, 0, stream>>>(a3, bf4, b4, 256,
                                                  K[3][0], K[3][1], a4);
  k_bconv7<8><<<dim3(64, 8, 4), 256, 0, stream>>>(a4, bf5, b5, 512,
                                                  K[4][0], K[4][1], a5);
  k_bconv7<16><<<dim3(64, 8, 4), 256, 0, stream>>>(a5, bf6, b6, 512,
                                                   K[5][0], K[5][1], a6);
  k_repack<<<(4096 * 256 + 255) / 256, 256, 0, stream>>>(a6, f0);
  k_fct<256><<<dim3(128, 16), 256, 0, stream>>>(f0, pfw1, fb1, 1024,
                                                K[6][0], K[6][1], f1);
  k_fct<32><<<dim3(128, 16), 256, 0, stream>>>(f1, pfw2, fb2, 1024,
                                               K[7][0], K[7][1], f2);
  k_fc3<<<4096, 64, 0, stream>>>(f2, pfw3, fb3, K[8][0], K[8][1],
                                 (float*)d_out);
}